// Round 6
// baseline (3919.752 us; speedup 1.0000x reference)
//
#include <hip/hip_runtime.h>
#include <hip/hip_bf16.h>
#include <stdint.h>

#define T_STEPS 256
#define BATCH   64
#define HID     512
#define HALF    256
#define NCOLS   1536              // [zr1:512 | g1:256 | zr2:512 | g2:256]
#define MROWS   (T_STEPS * BATCH) // 16384
#define SLICE_N 100
#define SAVED_OFF (2 * BATCH * HID) // 65536 floats into d_out

// P layout: [g4][t][slot:12][wt:8][lane:64][rr:4] f32
#define PSLOT 2048              // 8*64*4 floats
#define PSTEP (12 * PSLOT)      // floats per (g4, t)

#define RING_D 32               // P1 ring depth (timesteps); lives in dead X0
#define NHELP 24                // helper WGs = 1536/64 column tiles

// col-split recurrence: 8 WGs per layer, weights LDS-resident (96KB/WG).
// Exchange buffers (global, A-fragment order): elem (row,k) at
// ((a*8+kt)*64 + ((row&15)|(((k&31)>>3)<<4)))*8 + (k&7), a=row>>4, kt=k>>5.
#define XBUF 16384              // bf16 elems per exchange buffer (32KB)
#define WG_FRAGS 6144           // 16B frags per (layer,j) weight slice (96KB)

typedef short bf16x8 __attribute__((ext_vector_type(8)));
typedef float f32x4  __attribute__((ext_vector_type(4)));

__device__ __forceinline__ f32x4 mfma16(bf16x8 a, bf16x8 b, f32x4 c) {
  return __builtin_amdgcn_mfma_f32_16x16x32_bf16(a, b, c, 0, 0, 0);
}
__device__ __forceinline__ float sigm_f(float x) {
  return __builtin_amdgcn_rcpf(1.f + __expf(-x));
}
__device__ __forceinline__ float tanh_f(float x) {
  x = fminf(fmaxf(x, -30.f), 30.f);
  float e = __expf(-2.f * x);
  return (1.f - e) * __builtin_amdgcn_rcpf(1.f + e);
}

// memory-side-coherent ops (bypass L1/L2; visible at L3 = agent coherence point).
// Writer protocol: coh stores -> s_waitcnt vmcnt(0) (wave) -> wave-count -> flag.
// Reader protocol: poll flag -> coh loads. No cache-wide fences anywhere.
__device__ __forceinline__ unsigned long long coh_u64(const void* p) {
  return __hip_atomic_load((const unsigned long long*)p, __ATOMIC_RELAXED,
                           __HIP_MEMORY_SCOPE_AGENT);
}
__device__ __forceinline__ void coh_store_u64(void* p, unsigned long long v) {
  __hip_atomic_store((unsigned long long*)p, v, __ATOMIC_RELAXED,
                     __HIP_MEMORY_SCOPE_AGENT);
}
__device__ __forceinline__ bf16x8 coh_frag(const void* p) {
  union { unsigned long long u[2]; bf16x8 v; } x;
  x.u[0] = coh_u64(p);
  x.u[1] = coh_u64((const char*)p + 8);
  return x.v;
}
__device__ __forceinline__ float4 coh_f4(const void* p) {
  union { unsigned long long u[2]; float4 v; } x;
  x.u[0] = coh_u64(p);
  x.u[1] = coh_u64((const char*)p + 8);
  return x.v;
}

#define POLLGE(addr, val)                                                        \
  while (__hip_atomic_load((addr), __ATOMIC_RELAXED, __HIP_MEMORY_SCOPE_AGENT) < \
         (uint32_t)(val))                                                        \
    __builtin_amdgcn_s_sleep(1);

// compiler reorder fence (no codegen)
#define CFENCE() asm volatile("" ::: "memory")
// wave-level drain of own VMEM stores (coh stores ack at L3)
#define WAVE_VM() asm volatile("s_waitcnt vmcnt(0)" ::: "memory")

struct AllW {
  const float* W[8]; // l0: zr1,g1,zr2,g2 ; l1: zr1,g1,zr2,g2
  const float* b[8];
};

// ---------------------------------------------------------------- prep
// Wcs: [l][j][g:96][lane:64] 16B frags. g<32: zr1 (ct=g>>3, kt=g&7);
// 32..47: g1; 48..79: zr2; 80..95: g2. zr ct<2 -> z cols 32j+16ct,
// zr ct>=2 -> r cols 256+32j+16(ct-2); g: cols 32j+16ct.
__global__ void prep_weights(AllW aw, __hip_bfloat16* __restrict__ Wcs,
                             __hip_bfloat16* __restrict__ WxT,
                             float* __restrict__ biasAll,
                             uint32_t* __restrict__ flags) {
  int tid = blockIdx.x * blockDim.x + threadIdx.x;
  if (tid < 4096) flags[tid] = 0u;   // zero all sync flags every launch
  const int NWc = 2 * 8 * WG_FRAGS;  // 98304
  const int NX = 2 * NCOLS * 64;
  if (tid < NWc) {
    int l = tid / (8 * WG_FRAGS), r = tid % (8 * WG_FRAGS);
    int j = r / WG_FRAGS, r2 = r % WG_FRAGS;
    int g = r2 >> 6, lane = r2 & 63;
    int lrow = lane & 15, lgrp = lane >> 4;
    int s, gg;
    if (g < 32)      { s = 0; gg = g; }
    else if (g < 48) { s = 1; gg = g - 32; }
    else if (g < 80) { s = 2; gg = g - 48; }
    else             { s = 3; gg = g - 80; }
    int ct = gg >> 3, kt = gg & 7;
    int zr = (s == 0 || s == 2);
    int nc = zr ? 512 : 256;
    int cb = zr ? (ct < 2 ? 32 * j + 16 * ct : 256 + 32 * j + 16 * (ct - 2))
                : (32 * j + 16 * ct);
    const float* W = aw.W[l * 4 + s];
    int kbase = 512 + kt * 32 + lgrp * 8;
    __hip_bfloat16 frag[8];
#pragma unroll
    for (int e = 0; e < 8; ++e)
      frag[e] = __float2bfloat16(W[(size_t)(kbase + e) * nc + cb + lrow]);
    *(uint4*)&Wcs[(size_t)tid * 8] = *(uint4*)frag;
  } else if (tid < NWc + NX) {
    int u = tid - NWc;
    int l = u / (NCOLS * 64), r = u % (NCOLS * 64);
    int c = r >> 6, k0 = (r & 63) * 8;
    const float* W; int nc, cc;
    if (c < 512)       { W = aw.W[l*4+0]; nc = 512; cc = c;        }
    else if (c < 768)  { W = aw.W[l*4+1]; nc = 256; cc = c - 512;  }
    else if (c < 1280) { W = aw.W[l*4+2]; nc = 512; cc = c - 768;  }
    else               { W = aw.W[l*4+3]; nc = 256; cc = c - 1280; }
    __hip_bfloat16 frag[8];
#pragma unroll
    for (int e = 0; e < 8; ++e)
      frag[e] = __float2bfloat16(W[(size_t)(k0 + e) * nc + cc]);
    *(uint4*)&WxT[((size_t)l * NCOLS + c) * 512 + k0] = *(uint4*)frag;
  } else if (tid < NWc + NX + 2 * NCOLS) {
    int c = tid - NWc - NX;
    int l = c / NCOLS, cc = c % NCOLS;
    const float* b; int off;
    if (cc < 512)       { b = aw.b[l*4+0]; off = cc;        }
    else if (cc < 768)  { b = aw.b[l*4+1]; off = cc - 512;  }
    else if (cc < 1280) { b = aw.b[l*4+2]; off = cc - 768;  }
    else                { b = aw.b[l*4+3]; off = cc - 1280; }
    biasAll[c] = b[off];
  }
}

// ---------------------------------------------------------------- embed gather
__global__ void embed_gather(const int* __restrict__ seq, const float* __restrict__ emb,
                             __hip_bfloat16* __restrict__ X0) {
  int i = blockIdx.x * blockDim.x + threadIdx.x;
  int row = i >> 7, c4 = (i & 127) * 4;
  int idx = seq[row];
  float4 v = *(const float4*)&emb[(size_t)idx * HID + c4];
  union { __hip_bfloat16 h[4]; uint2 u; } pk;
  pk.h[0] = __float2bfloat16(v.x);
  pk.h[1] = __float2bfloat16(v.y);
  pk.h[2] = __float2bfloat16(v.z);
  pk.h[3] = __float2bfloat16(v.w);
  *(uint2*)&X0[(size_t)row * HID + c4] = pk.u;
}

// ---------------------------------------------------------------- P0 = X0 @ WxT^T + bias
__global__ __launch_bounds__(256) void gemm_p(const __hip_bfloat16* __restrict__ A,
                                              const __hip_bfloat16* __restrict__ WT,
                                              const float* __restrict__ bias,
                                              float* __restrict__ Psw) {
  const int tid = threadIdx.x;
  const int lane = tid & 63, w = tid >> 6;
  const int lrow = lane & 15, lgrp = lane >> 4;
  const int n0 = blockIdx.x * 64, m0 = blockIdx.y * 64;
  const int wm = w & 1, wn = w >> 1;
  __shared__ __hip_bfloat16 As[64][72];
  f32x4 acc[2][2];
#pragma unroll
  for (int a = 0; a < 2; ++a)
#pragma unroll
    for (int b = 0; b < 2; ++b) acc[a][b] = (f32x4){0.f, 0.f, 0.f, 0.f};

  const int lr = tid >> 2, lc = (tid & 3) * 16;
  for (int k0 = 0; k0 < 512; k0 += 64) {
    *(uint4*)&As[lr][lc]     = *(const uint4*)&A[((size_t)m0 + lr) * 512 + k0 + lc];
    *(uint4*)&As[lr][lc + 8] = *(const uint4*)&A[((size_t)m0 + lr) * 512 + k0 + lc + 8];
    __syncthreads();
#pragma unroll
    for (int kt = 0; kt < 2; ++kt) {
      bf16x8 a0 = *(const bf16x8*)&As[wm * 32 + lrow][kt * 32 + lgrp * 8];
      bf16x8 a1 = *(const bf16x8*)&As[wm * 32 + 16 + lrow][kt * 32 + lgrp * 8];
      bf16x8 b0 = *(const bf16x8*)&WT[((size_t)n0 + wn * 32 + lrow) * 512 + k0 + kt * 32 + lgrp * 8];
      bf16x8 b1 = *(const bf16x8*)&WT[((size_t)n0 + wn * 32 + 16 + lrow) * 512 + k0 + kt * 32 + lgrp * 8];
      acc[0][0] = mfma16(a0, b0, acc[0][0]);
      acc[0][1] = mfma16(a0, b1, acc[0][1]);
      acc[1][0] = mfma16(a1, b0, acc[1][0]);
      acc[1][1] = mfma16(a1, b1, acc[1][1]);
    }
    __syncthreads();
  }
  const int t = m0 >> 6;
#pragma unroll
  for (int mt = 0; mt < 2; ++mt) {
    int g = wm * 2 + mt;
#pragma unroll
    for (int nt = 0; nt < 2; ++nt) {
      int colb = n0 + wn * 32 + nt * 16; // wave-uniform
      int slot, wt;
      if (colb < 512)       { int c = colb;        wt = (c & 255) >> 5; slot = (c >> 8) * 2 + ((c >> 4) & 1); }
      else if (colb < 768)  { int c = colb - 512;  wt = c >> 5;         slot = 4 + ((c >> 4) & 1); }
      else if (colb < 1280) { int c = colb - 768;  wt = (c & 255) >> 5; slot = 6 + (c >> 8) * 2 + ((c >> 4) & 1); }
      else                  { int c = colb - 1280; wt = c >> 5;         slot = 10 + ((c >> 4) & 1); }
      float bv = bias[colb + lrow];
      float4 v;
      v.x = acc[mt][nt][0] + bv;
      v.y = acc[mt][nt][1] + bv;
      v.z = acc[mt][nt][2] + bv;
      v.w = acc[mt][nt][3] + bv;
      size_t off = (((size_t)g * 256 + t) * 12 + slot) * PSLOT + (size_t)wt * 256 + (size_t)lane * 4;
      *(float4*)&Psw[off] = v;
    }
  }
}

// ---------------------------------------------------------------- fused pipeline
// blocks 0-7  : layer-0 recurrence, col-split j=bid   (96KB weights in LDS)
// blocks 8-15 : layer-1 recurrence, col-split j=bid-8
// blocks 16-39: P1 helpers (read h0 frags from exchange ring)
struct SharedMem {
  union {
    struct {
      __hip_bfloat16 Wl[WG_FRAGS * 8];  // 96KB weight slice
      __hip_bfloat16 Ab[XBUF];          // 32KB stage A-fragment buffer
      __hip_bfloat16 st[2048];          // 4KB exchange staging (frag layout, own j slice)
      float zl[2048];                   // [64][32] z values
      float h1s[2048];                  // [64][32] own-col h1 (f32 master copy)
      float h2s[2048];                  // [64][32] own-col h2
      uint32_t fcnt[8];                 // per-stage wave-completion counters
    } rec;                              // ~156KB
    struct {
      __hip_bfloat16 Bs[64][520];       // 66.5KB Wx slice
      __hip_bfloat16 As[2 * XBUF];      // 64KB h0 frags (h1|h2)
      float bias[64];
    } hlp;
  };
};

template <int LAYER>
__device__ __forceinline__ const float* paddr(const float* Pb, int g4, int t,
                                              int slot, int j, int lane) {
  size_t tt = LAYER ? (size_t)(t & (RING_D - 1)) : (size_t)t;
  size_t TD = LAYER ? RING_D : 256;
  return Pb + (((size_t)g4 * TD + tt) * 12 + slot) * PSLOT + (size_t)j * 256 +
         (size_t)lane * 4;
}

// stage Ab fill: frag f = q*512 + tid (lane-contiguous 16B ds_write, no conflicts)
#define AB_FILL(srcbuf)                                                      \
  {                                                                          \
    const char* sp = (const char*)(srcbuf) + (size_t)tid * 16;               \
    bf16x8 t0 = coh_frag(sp);                                                \
    bf16x8 t1 = coh_frag(sp + 8192);                                         \
    bf16x8 t2 = coh_frag(sp + 16384);                                        \
    bf16x8 t3 = coh_frag(sp + 24576);                                        \
    *(bf16x8*)&Ab[((size_t)0 * 512 + tid) * 8] = t0;                         \
    *(bf16x8*)&Ab[((size_t)1 * 512 + tid) * 8] = t1;                         \
    *(bf16x8*)&Ab[((size_t)2 * 512 + tid) * 8] = t2;                         \
    *(bf16x8*)&Ab[((size_t)3 * 512 + tid) * 8] = t3;                         \
  }

// per-wave completion: lane0 bumps LDS counter; 8th wave publishes global flag
#define WAVE_FLAG(sidx, gflag)                                               \
  if (lane == 0) {                                                           \
    int sl_ = ((unsigned)t * 4 + (sidx)) & 7;                                \
    uint32_t old_ = atomicAdd(&fcnt[sl_], 1u);                               \
    if (old_ == 7) {                                                         \
      fcnt[sl_] = 0;                                                         \
      __hip_atomic_fetch_add((gflag), 1u, __ATOMIC_RELAXED,                  \
                             __HIP_MEMORY_SCOPE_AGENT);                      \
    }                                                                        \
  }

template <int LAYER>
__device__ void rec_body(const __hip_bfloat16* __restrict__ Wcs_j,
                         const float* __restrict__ Pbase,  // L0: Psw0; L1: P1 ring
                         __hip_bfloat16* __restrict__ R,   // exchange ring area
                         float* __restrict__ out,
                         uint32_t* __restrict__ flags,
                         SharedMem& sm, int j) {
  const int tid = threadIdx.x;
  const int lane = tid & 63, w = tid >> 6;      // 8 waves
  const int lrow = lane & 15, lgrp = lane >> 4;

  uint32_t* F = flags + LAYER * 1024;           // f[s][t] = F[s*256+t]
  uint32_t* cnt1 = flags + 2048;
  uint32_t* l1prog = flags + 2304;

  __hip_bfloat16* const Wl = sm.rec.Wl;
  __hip_bfloat16* const Ab = sm.rec.Ab;
  __hip_bfloat16* const st = sm.rec.st;
  float* const zl  = sm.rec.zl;
  float* const h1s = sm.rec.h1s;
  float* const h2s = sm.rec.h2s;
  uint32_t* const fcnt = sm.rec.fcnt;

  const int HM = LAYER ? 1 : 7;                 // h ring mask (depth 2 / 8)
  __hip_bfloat16* const h1r = R + (size_t)(LAYER ? 20 : 0)  * XBUF;
  __hip_bfloat16* const h2r = R + (size_t)(LAYER ? 22 : 8)  * XBUF;
  __hip_bfloat16* const ag1 = R + (size_t)(LAYER ? 24 : 16) * XBUF;
  __hip_bfloat16* const ag2 = R + (size_t)(LAYER ? 26 : 18) * XBUF;

  // one-time init: weights -> LDS, h slices -> 0, saved page 0 -> 0
  for (int i = tid; i < WG_FRAGS; i += 512)
    *(bf16x8*)&Wl[(size_t)i * 8] = *(const bf16x8*)&Wcs_j[(size_t)i * 8];
  for (int i = tid; i < 2048; i += 512) { h1s[i] = 0.f; h2s[i] = 0.f; }
  if (tid < 8) fcnt[tid] = 0u;
  if (LAYER == 1)
    for (int i = tid; i < 64 * 32; i += 512) {
      int row = i >> 5, c = 32 * j + (i & 31);
      if (c < SLICE_N) out[SAVED_OFF + (size_t)row * SLICE_N + c] = 0.f;
    }
  __syncthreads();

  // stage-1/3 wave constants: ct13 0,1 = z-tiles, 2,3 = r-tiles; 2 row-tiles
  const int ct13 = w >> 1, a0 = (w & 1) * 2, a1 = a0 + 1;
  const int cl13 = 16 * (ct13 & 1) + lrow;
  const int lt13 = (lgrp * 4) | ((cl13 >> 3) << 4);
  const int el13 = cl13 & 7;
  // stage-2/4 wave constants: ct24 0,1 g-tiles; a24 row-tile
  const int ct24 = w >> 2, a24 = w & 3;
  const int cl24 = 16 * ct24 + lrow;
  const int lt24 = (lgrp * 4) | ((cl24 >> 3) << 4);
  const int el24 = cl24 & 7;
  const int col24 = 32 * j + cl24;
  const int row24 = a24 * 16 + lgrp * 4;
  // publish word constants: lane -> (word row, el-half)
  const int pu = lane >> 1, phf = (lane & 1) * 4;
  const int plt13 = (ct13 & 1) * 32 + pu;   // stage-1/3 word row
  const int plt24 = ct24 * 32 + pu;         // stage-2/4 word row

  const float Q23 = 8388608.f, IQ23 = 1.f / 8388608.f;
  const float Q10 = 1024.f,    IQ10 = 1.f / 1024.f;

  float hr1[4] = {0.f, 0.f, 0.f, 0.f};
  float hr2[4] = {0.f, 0.f, 0.f, 0.f};

  for (int t = 0; t < T_STEPS; ++t) {
    auto LDP = [&](int g, int slot) -> float4 {
      const float* a = paddr<LAYER>(Pbase, g, t, slot, j, lane);
      if (LAYER == 1) return coh_f4(a);       // ring reuse -> must bypass caches
      return *(const float4*)a;
    };
    float4 P_s1_0, P_s1_1, P_s2, P_s3_0, P_s3_1, P_s4;
    if (LAYER == 0) {                          // independent of flags: overlap poll
      P_s1_0 = LDP(a0, ct13);      P_s1_1 = LDP(a1, ct13);
      P_s2   = LDP(a24, 4 + ct24);
      P_s3_0 = LDP(a0, 6 + ct13);  P_s3_1 = LDP(a1, 6 + ct13);
      P_s4   = LDP(a24, 10 + ct24);
    }

    // ================== stage 1: zr1 = sigma(P + h2 @ Uzr1)
    if (lane == 0) {
      if (LAYER == 1) { POLLGE(&cnt1[t], NHELP); }
      if (t > 0)      { POLLGE(&F[3 * 256 + t - 1], 8); }
      if (LAYER == 1 && tid == 0 && t > 0)   // step t-1 fully retired (incl. P loads)
        __hip_atomic_store(&l1prog[j], (uint32_t)t, __ATOMIC_RELAXED, __HIP_MEMORY_SCOPE_AGENT);
    }
    CFENCE();
    if (LAYER == 1) {
      P_s1_0 = LDP(a0, ct13);      P_s1_1 = LDP(a1, ct13);
      P_s2   = LDP(a24, 4 + ct24);
      P_s3_0 = LDP(a0, 6 + ct13);  P_s3_1 = LDP(a1, 6 + ct13);
      P_s4   = LDP(a24, 10 + ct24);
    }
    if (t == 0) {
      bf16x8 zz = {0, 0, 0, 0, 0, 0, 0, 0};
#pragma unroll
      for (int q = 0; q < 4; ++q) *(bf16x8*)&Ab[((size_t)q * 512 + tid) * 8] = zz;
    } else {
      AB_FILL(&h2r[(size_t)((t - 1) & HM) * XBUF]);
    }
    __syncthreads();
    {
      f32x4 c0 = (f32x4){0.f, 0.f, 0.f, 0.f}, c1 = c0;
#pragma unroll
      for (int kt = 0; kt < 8; ++kt) {
        bf16x8 A0 = *(const bf16x8*)&Ab[((a0 * 8 + kt) * 64 + lane) * 8];
        bf16x8 A1 = *(const bf16x8*)&Ab[((a1 * 8 + kt) * 64 + lane) * 8];
        bf16x8 B  = *(const bf16x8*)&Wl[((ct13 * 8 + kt) * 64 + lane) * 8];
        c0 = mfma16(A0, B, c0);
        c1 = mfma16(A1, B, c1);
      }
      if (ct13 < 2) {
#pragma unroll
        for (int rr = 0; rr < 4; ++rr) {
          zl[(a0 * 16 + lgrp * 4 + rr) * 32 + cl13] = 0.875f * sigm_f(c0[rr] + P_s1_0[rr]) + 0.125f;
          zl[(a1 * 16 + lgrp * 4 + rr) * 32 + cl13] = 0.875f * sigm_f(c1[rr] + P_s1_1[rr]) + 0.125f;
        }
      } else {
#pragma unroll
        for (int rr = 0; rr < 4; ++rr) {
          float r0 = sigm_f(c0[rr] + P_s1_0[rr]);
          float r1 = sigm_f(c1[rr] + P_s1_1[rr]);
          st[(a0 * 64 + lt13 + rr) * 8 + el13] =
              __float2bfloat16(r0 * h2s[(a0 * 16 + lgrp * 4 + rr) * 32 + cl13]);
          st[(a1 * 64 + lt13 + rr) * 8 + el13] =
              __float2bfloat16(r1 * h2s[(a1 * 16 + lgrp * 4 + rr) * 32 + cl13]);
        }
        CFENCE();   // DS in-order per wave: reads below see writes above
        __hip_bfloat16* dst = &ag1[(size_t)(t & 1) * XBUF];
        unsigned long long v0 = *(const unsigned long long*)&st[(a0 * 64 + plt13) * 8 + phf];
        unsigned long long v1 = *(const unsigned long long*)&st[(a1 * 64 + plt13) * 8 + phf];
        coh_store_u64(&dst[((size_t)(a0 * 8 + j) * 64 + plt13) * 8 + phf], v0);
        coh_store_u64(&dst[((size_t)(a1 * 8 + j) * 64 + plt13) * 8 + phf], v1);
        WAVE_VM();
      }
    }
    WAVE_FLAG(0, &F[0 * 256 + t]);

    // ================== stage 2: g1 = tanh(P + ag1 @ Ug1); h1 update
    if (lane == 0) {
      POLLGE(&F[0 * 256 + t], 8);
      if (LAYER == 0 && t >= 8) { POLLGE(&cnt1[t - 8], NHELP); } // h-ring WAR vs helpers
    }
    CFENCE();
    AB_FILL(&ag1[(size_t)(t & 1) * XBUF]);
    __syncthreads();
    {
      f32x4 c = (f32x4){0.f, 0.f, 0.f, 0.f};
#pragma unroll
      for (int kt = 0; kt < 8; ++kt) {
        bf16x8 A = *(const bf16x8*)&Ab[((a24 * 8 + kt) * 64 + lane) * 8];
        bf16x8 B = *(const bf16x8*)&Wl[((32 + ct24 * 8 + kt) * 64 + lane) * 8];
        c = mfma16(A, B, c);
      }
#pragma unroll
      for (int rr = 0; rr < 4; ++rr) {
        float gv = tanh_f(c[rr] + P_s2[rr]);
        float z  = zl[(row24 + rr) * 32 + cl24];
        float zq = floorf(z * Q10) * IQ10;
        float h = hr1[rr];
        h = floorf(h * zq * Q23) * IQ23;
        h = h + rintf((1.f - z) * gv * Q23) * IQ23;
        hr1[rr] = h;
        h1s[(row24 + rr) * 32 + cl24] = h;
        st[(a24 * 64 + lt24 + rr) * 8 + el24] = __float2bfloat16(h);
        int row = row24 + rr;
        if (LAYER == 1 && col24 < SLICE_N)
          out[SAVED_OFF + (size_t)(t + 1) * (BATCH * SLICE_N) + (size_t)row * SLICE_N + col24] = h;
        if (t == T_STEPS - 1)
          out[(size_t)LAYER * (BATCH * HID) + (size_t)row * HID + col24] = h;
      }
      CFENCE();
      __hip_bfloat16* dst = &h1r[(size_t)(t & HM) * XBUF];
      unsigned long long v = *(const unsigned long long*)&st[(a24 * 64 + plt24) * 8 + phf];
      coh_store_u64(&dst[((size_t)(a24 * 8 + j) * 64 + plt24) * 8 + phf], v);
      WAVE_VM();
    }
    WAVE_FLAG(1, &F[1 * 256 + t]);

    // ================== stage 3: zr2 = sigma(P + h1 @ Uzr2)
    if (lane == 0) { POLLGE(&F[1 * 256 + t], 8); }
    CFENCE();
    AB_FILL(&h1r[(size_t)(t & HM) * XBUF]);
    __syncthreads();
    {
      f32x4 c0 = (f32x4){0.f, 0.f, 0.f, 0.f}, c1 = c0;
#pragma unroll
      for (int kt = 0; kt < 8; ++kt) {
        bf16x8 A0 = *(const bf16x8*)&Ab[((a0 * 8 + kt) * 64 + lane) * 8];
        bf16x8 A1 = *(const bf16x8*)&Ab[((a1 * 8 + kt) * 64 + lane) * 8];
        bf16x8 B  = *(const bf16x8*)&Wl[((48 + ct13 * 8 + kt) * 64 + lane) * 8];
        c0 = mfma16(A0, B, c0);
        c1 = mfma16(A1, B, c1);
      }
      if (ct13 < 2) {
#pragma unroll
        for (int rr = 0; rr < 4; ++rr) {
          zl[(a0 * 16 + lgrp * 4 + rr) * 32 + cl13] = 0.875f * sigm_f(c0[rr] + P_s3_0[rr]) + 0.125f;
          zl[(a1 * 16 + lgrp * 4 + rr) * 32 + cl13] = 0.875f * sigm_f(c1[rr] + P_s3_1[rr]) + 0.125f;
        }
      } else {
#pragma unroll
        for (int rr = 0; rr < 4; ++rr) {
          float r0 = sigm_f(c0[rr] + P_s3_0[rr]);
          float r1 = sigm_f(c1[rr] + P_s3_1[rr]);
          st[(a0 * 64 + lt13 + rr) * 8 + el13] =
              __float2bfloat16(r0 * h1s[(a0 * 16 + lgrp * 4 + rr) * 32 + cl13]);
          st[(a1 * 64 + lt13 + rr) * 8 + el13] =
              __float2bfloat16(r1 * h1s[(a1 * 16 + lgrp * 4 + rr) * 32 + cl13]);
        }
        CFENCE();
        __hip_bfloat16* dst = &ag2[(size_t)(t & 1) * XBUF];
        unsigned long long v0 = *(const unsigned long long*)&st[(a0 * 64 + plt13) * 8 + phf];
        unsigned long long v1 = *(const unsigned long long*)&st[(a1 * 64 + plt13) * 8 + phf];
        coh_store_u64(&dst[((size_t)(a0 * 8 + j) * 64 + plt13) * 8 + phf], v0);
        coh_store_u64(&dst[((size_t)(a1 * 8 + j) * 64 + plt13) * 8 + phf], v1);
        WAVE_VM();
      }
    }
    WAVE_FLAG(2, &F[2 * 256 + t]);

    // ================== stage 4: g2 = tanh(P + ag2 @ Ug2); h2 update
    if (lane == 0) { POLLGE(&F[2 * 256 + t], 8); }
    CFENCE();
    AB_FILL(&ag2[(size_t)(t & 1) * XBUF]);
    __syncthreads();
    {
      f32x4 c = (f32x4){0.f, 0.f, 0.f, 0.f};
#pragma unroll
      for (int kt = 0; kt < 8; ++kt) {
        bf16x8 A = *(const bf16x8*)&Ab[((a24 * 8 + kt) * 64 + lane) * 8];
        bf16x8 B = *(const bf16x8*)&Wl[((80 + ct24 * 8 + kt) * 64 + lane) * 8];
        c = mfma16(A, B, c);
      }
#pragma unroll
      for (int rr = 0; rr < 4; ++rr) {
        float gv = tanh_f(c[rr] + P_s4[rr]);
        float z  = zl[(row24 + rr) * 32 + cl24];
        float zq = floorf(z * Q10) * IQ10;
        float h = hr2[rr];
        h = floorf(h * zq * Q23) * IQ23;
        h = h + rintf((1.f - z) * gv * Q23) * IQ23;
        hr2[rr] = h;
        h2s[(row24 + rr) * 32 + cl24] = h;
        st[(a24 * 64 + lt24 + rr) * 8 + el24] = __float2bfloat16(h);
        int row = row24 + rr;
        if (t == T_STEPS - 1)
          out[(size_t)LAYER * (BATCH * HID) + (size_t)row * HID + HALF + col24] = h;
      }
      CFENCE();
      __hip_bfloat16* dst = &h2r[(size_t)(t & HM) * XBUF];
      unsigned long long v = *(const unsigned long long*)&st[(a24 * 64 + plt24) * 8 + phf];
      coh_store_u64(&dst[((size_t)(a24 * 8 + j) * 64 + plt24) * 8 + phf], v);
      WAVE_VM();
    }
    WAVE_FLAG(3, &F[3 * 256 + t]);
  }
}

// helper: P1(t)[:, n0:n0+64] = h0(t) @ Wx1-slice + bias. A-frags come from the
// layer-0 h exchange ring (identical bf16 values / K-order as before).
__device__ void helper_body(const __hip_bfloat16* __restrict__ WxT1,
                            const float* __restrict__ bias1,
                            const __hip_bfloat16* __restrict__ R,
                            float* __restrict__ P1ring,
                            uint32_t* __restrict__ flags,
                            SharedMem& sm, int n) {
  const int tid = threadIdx.x;
  const int lane = tid & 63, w = tid >> 6;
  const int lrow = lane & 15, lgrp = lane >> 4;
  const int n0 = n * 64;

  uint32_t* F0 = flags;                  // layer-0 stage flags
  uint32_t* cnt1 = flags + 2048;
  uint32_t* l1prog = flags + 2304;
  const __hip_bfloat16* h1r = R;         // L0 h rings (depth 8)
  const __hip_bfloat16* h2r = R + (size_t)8 * XBUF;

  for (int i = tid; i < 64 * 64; i += 512) {
    int c = i >> 6, k8 = (i & 63) * 8;
    *(bf16x8*)&sm.hlp.Bs[c][k8] = *(const bf16x8*)&WxT1[(size_t)(n0 + c) * 512 + k8];
  }
  if (tid < 64) sm.hlp.bias[tid] = bias1[n0 + tid];
  __syncthreads();

  const int mt = w & 3, chb = (w >> 2) * 2;   // row-tile, col-subtile pair

  for (int t = 0; t < T_STEPS; ++t) {
    if (lane == 0) {
      POLLGE(&F0[3 * 256 + t], 8);            // h1,h2 of step t published
      if (t >= RING_D) {                      // P1-ring WAR vs layer-1
        for (;;) {
          uint32_t mm = 0xffffffffu;
#pragma unroll
          for (int q = 0; q < 8; ++q) {
            uint32_t v = __hip_atomic_load(&l1prog[q], __ATOMIC_RELAXED, __HIP_MEMORY_SCOPE_AGENT);
            mm = v < mm ? v : mm;
          }
          if (mm + (uint32_t)(RING_D - 1) >= (uint32_t)t) break;
          __builtin_amdgcn_s_sleep(1);
        }
      }
    }
    CFENCE();
    {
      const char* s1 = (const char*)&h1r[(size_t)(t & 7) * XBUF] + (size_t)tid * 16;
      const char* s2 = (const char*)&h2r[(size_t)(t & 7) * XBUF] + (size_t)tid * 16;
      bf16x8 tA[8];
#pragma unroll
      for (int k = 0; k < 4; ++k) tA[k] = coh_frag(s1 + (size_t)k * 8192);
#pragma unroll
      for (int k = 4; k < 8; ++k) tA[k] = coh_frag(s2 + (size_t)(k - 4) * 8192);
#pragma unroll
      for (int k = 0; k < 8; ++k) *(bf16x8*)&sm.hlp.As[(size_t)(k * 512 + tid) * 8] = tA[k];
    }
    __syncthreads();
#pragma unroll
    for (int q = 0; q < 2; ++q) {
      int ch = chb + q;
      f32x4 c = (f32x4){0.f, 0.f, 0.f, 0.f};
#pragma unroll
      for (int kt = 0; kt < 16; ++kt) {
        const bf16x8 A = *(const bf16x8*)&sm.hlp.As[
            kt < 8 ? (size_t)((mt * 8 + kt) * 64 + lane) * 8
                   : (size_t)XBUF + (size_t)((mt * 8 + (kt - 8)) * 64 + lane) * 8];
        const bf16x8 B = *(const bf16x8*)&sm.hlp.Bs[ch * 16 + lrow][kt * 32 + lgrp * 8];
        c = mfma16(A, B, c);
      }
      int colb = n0 + ch * 16;               // wave-uniform
      int slot, wt;
      if (colb < 512)       { int cc = colb;        wt = (cc & 255) >> 5; slot = (cc >> 8) * 2 + ((cc >> 4) & 1); }
      else if (colb < 768)  { int cc = colb - 512;  wt = cc >> 5;         slot = 4 + ((cc >> 4) & 1); }
      else if (colb < 1280) { int cc = colb - 768;  wt = (cc & 255) >> 5; slot = 6 + (cc >> 8) * 2 + ((cc >> 4) & 1); }
      else                  { int cc = colb - 1280; wt = cc >> 5;         slot = 10 + ((cc >> 4) & 1); }
      float bv = sm.hlp.bias[ch * 16 + lrow];
      union { float4 f; unsigned long long u[2]; } uv;
      uv.f.x = c[0] + bv; uv.f.y = c[1] + bv; uv.f.z = c[2] + bv; uv.f.w = c[3] + bv;
      size_t off = (((size_t)mt * RING_D + (t & (RING_D - 1))) * 12 + slot) * PSLOT +
                   (size_t)wt * 256 + (size_t)lane * 4;
      unsigned long long* d = (unsigned long long*)&P1ring[off];
      coh_store_u64(d, uv.u[0]);
      coh_store_u64(d + 1, uv.u[1]);
    }
    __syncthreads();   // drains vmcnt: all coherent stores visible at L3
    if (tid == 0)
      __hip_atomic_fetch_add(&cnt1[t], 1u, __ATOMIC_RELAXED, __HIP_MEMORY_SCOPE_AGENT);
  }
}

__global__ __attribute__((amdgpu_waves_per_eu(2))) __launch_bounds__(512)
void fused_kernel(const __hip_bfloat16* __restrict__ Wcs,
                  const float* __restrict__ Psw0,
                  float* __restrict__ P1ring,
                  const __hip_bfloat16* __restrict__ WxT1,
                  const float* __restrict__ bias1,
                  float* __restrict__ out,
                  __hip_bfloat16* __restrict__ R,
                  uint32_t* __restrict__ flags) {
  __shared__ SharedMem sm;
  const int bid = blockIdx.x;
  if (bid < 8)
    rec_body<0>(Wcs + (size_t)bid * WG_FRAGS * 8, Psw0, R, out, flags, sm, bid);
  else if (bid < 16)
    rec_body<1>(Wcs + (size_t)(8 + (bid - 8)) * WG_FRAGS * 8, P1ring, R, out, flags, sm, bid - 8);
  else
    helper_body(WxT1, bias1, R, P1ring, flags, sm, bid - 16);
}

// ---------------------------------------------------------------- launch
extern "C" void kernel_launch(void* const* d_in, const int* in_sizes, int n_in,
                              void* d_out, int out_size, void* d_ws, size_t ws_size,
                              hipStream_t stream) {
  const int*   seq = (const int*)d_in[0];
  const float* emb = (const float*)d_in[1];
  AllW aw;
  for (int l = 0; l < 2; ++l)
    for (int s = 0; s < 4; ++s) {
      aw.W[l * 4 + s] = (const float*)d_in[2 + l * 8 + s * 2];
      aw.b[l * 4 + s] = (const float*)d_in[2 + l * 8 + s * 2 + 1];
    }

  uint8_t* wp = (uint8_t*)d_ws;
  float* Psw = (float*)wp;                   wp += (size_t)4 * 256 * PSTEP * 4;        // 100.7 MB (P0)
  __hip_bfloat16* X0 = (__hip_bfloat16*)wp;  wp += (size_t)MROWS * HID * 2;            // 16.8 MB (X0 -> P1 ring)
  __hip_bfloat16* R  = (__hip_bfloat16*)wp;  wp += (size_t)MROWS * HID * 2;            // 16.8 MB (exchange rings)
  __hip_bfloat16* Wcs = (__hip_bfloat16*)wp; wp += (size_t)2 * 8 * WG_FRAGS * 8 * 2;   // 1.6 MB
  __hip_bfloat16* WxT = (__hip_bfloat16*)wp; wp += (size_t)2 * NCOLS * 512 * 2;        // 3.1 MB
  float* biasAll = (float*)wp;               wp += (size_t)2 * NCOLS * 4;
  uint32_t* flags = (uint32_t*)wp;           wp += 16384;   // f[2][4][256] | cnt1[256] | l1prog[8]

  float* out = (float*)d_out;

  const int prepTot = 2 * 8 * WG_FRAGS + 2 * NCOLS * 64 + 2 * NCOLS;
  const int prepN = (prepTot + 255) / 256;
  prep_weights<<<prepN, 256, 0, stream>>>(aw, Wcs, WxT, biasAll, flags);
  embed_gather<<<(MROWS * 128) / 256, 256, 0, stream>>>(seq, emb, X0);

  gemm_p<<<dim3(24, 256), 256, 0, stream>>>(X0, WxT, biasAll, Psw);
  // X0 dead after gemm_p -> reuse as P1 ring (32 steps deep)
  fused_kernel<<<8 + 8 + NHELP, 512, 0, stream>>>(
      Wcs, Psw, (float*)X0, WxT + (size_t)NCOLS * 512, biasAll + NCOLS,
      out, R, flags);
}

// Round 8
// 3030.354 us; speedup vs baseline: 1.2935x; 1.2935x over previous
//
#include <hip/hip_runtime.h>
#include <hip/hip_bf16.h>
#include <stdint.h>

#define T_STEPS 256
#define BATCH   64
#define HID     512
#define HALF    256
#define NCOLS   1536              // [zr1:512 | g1:256 | zr2:512 | g2:256]
#define MROWS   (T_STEPS * BATCH) // 16384
#define SLICE_N 100
#define SAVED_OFF (2 * BATCH * HID) // 65536 floats into d_out

// P layout: [g4][t][slot:12][wt:8][lane:64][rr:4] f32
#define PSLOT 2048              // 8*64*4 floats
#define PSTEP (12 * PSLOT)      // floats per (g4, t)

#define RING_D 32               // P1 ring depth (timesteps); lives in dead X0
#define NHELP 24                // helper WGs = 1536/64 column tiles

// col-split recurrence: 8 WGs per layer, weights LDS-resident (96KB/WG).
// Exchange buffers (global, A-fragment order): elem (row,k) at
// ((a*8+kt)*64 + ((row&15)|(((k&31)>>3)<<4)))*8 + (k&7), a=row>>4, kt=k>>5.
#define XBUF 16384              // bf16 elems per exchange buffer (32KB)
#define WG_FRAGS 6144           // 16B frags per (layer,j) weight slice (96KB)

typedef short bf16x8 __attribute__((ext_vector_type(8)));
typedef float f32x4  __attribute__((ext_vector_type(4)));

__device__ __forceinline__ f32x4 mfma16(bf16x8 a, bf16x8 b, f32x4 c) {
  return __builtin_amdgcn_mfma_f32_16x16x32_bf16(a, b, c, 0, 0, 0);
}
__device__ __forceinline__ float sigm_f(float x) {
  return __builtin_amdgcn_rcpf(1.f + __expf(-x));
}
__device__ __forceinline__ float tanh_f(float x) {
  x = fminf(fmaxf(x, -30.f), 30.f);
  float e = __expf(-2.f * x);
  return (1.f - e) * __builtin_amdgcn_rcpf(1.f + e);
}

// memory-side-coherent ops (bypass L1/L2; visible at L3 = agent coherence point).
// Writer protocol: coh stores -> __syncthreads (compiler drains vmcnt0) -> tid0 flag.
// Reader protocol: tid0 polls flag -> __syncthreads -> coh loads. No cache fences.
__device__ __forceinline__ unsigned long long coh_u64(const void* p) {
  return __hip_atomic_load((const unsigned long long*)p, __ATOMIC_RELAXED,
                           __HIP_MEMORY_SCOPE_AGENT);
}
__device__ __forceinline__ void coh_store_u64(void* p, unsigned long long v) {
  __hip_atomic_store((unsigned long long*)p, v, __ATOMIC_RELAXED,
                     __HIP_MEMORY_SCOPE_AGENT);
}
__device__ __forceinline__ bf16x8 coh_frag(const void* p) {
  union { unsigned long long u[2]; bf16x8 v; } x;
  x.u[0] = coh_u64(p);
  x.u[1] = coh_u64((const char*)p + 8);
  return x.v;
}
__device__ __forceinline__ float4 coh_f4(const void* p) {
  union { unsigned long long u[2]; float4 v; } x;
  x.u[0] = coh_u64(p);
  x.u[1] = coh_u64((const char*)p + 8);
  return x.v;
}

#define POLLGE(addr, val)                                                        \
  while (__hip_atomic_load((addr), __ATOMIC_RELAXED, __HIP_MEMORY_SCOPE_AGENT) < \
         (uint32_t)(val))                                                        \
    __builtin_amdgcn_s_sleep(1);

// compiler reorder fence (no codegen); HW DS pipe is in-order per wave
#define CFENCE() asm volatile("" ::: "memory")

struct AllW {
  const float* W[8]; // l0: zr1,g1,zr2,g2 ; l1: zr1,g1,zr2,g2
  const float* b[8];
};

// ---------------------------------------------------------------- prep
// Wcs: [l][j][g:96][lane:64] 16B frags. g<32: zr1 (ct=g>>3, kt=g&7);
// 32..47: g1; 48..79: zr2; 80..95: g2. zr ct<2 -> z cols 32j+16ct,
// zr ct>=2 -> r cols 256+32j+16(ct-2); g: cols 32j+16ct.
__global__ void prep_weights(AllW aw, __hip_bfloat16* __restrict__ Wcs,
                             __hip_bfloat16* __restrict__ WxT,
                             float* __restrict__ biasAll,
                             uint32_t* __restrict__ flags) {
  int tid = blockIdx.x * blockDim.x + threadIdx.x;
  if (tid < 4096) flags[tid] = 0u;   // zero all sync flags every launch
  const int NWc = 2 * 8 * WG_FRAGS;  // 98304
  const int NX = 2 * NCOLS * 64;
  if (tid < NWc) {
    int l = tid / (8 * WG_FRAGS), r = tid % (8 * WG_FRAGS);
    int j = r / WG_FRAGS, r2 = r % WG_FRAGS;
    int g = r2 >> 6, lane = r2 & 63;
    int lrow = lane & 15, lgrp = lane >> 4;
    int s, gg;
    if (g < 32)      { s = 0; gg = g; }
    else if (g < 48) { s = 1; gg = g - 32; }
    else if (g < 80) { s = 2; gg = g - 48; }
    else             { s = 3; gg = g - 80; }
    int ct = gg >> 3, kt = gg & 7;
    int zr = (s == 0 || s == 2);
    int nc = zr ? 512 : 256;
    int cb = zr ? (ct < 2 ? 32 * j + 16 * ct : 256 + 32 * j + 16 * (ct - 2))
                : (32 * j + 16 * ct);
    const float* W = aw.W[l * 4 + s];
    int kbase = 512 + kt * 32 + lgrp * 8;
    __hip_bfloat16 frag[8];
#pragma unroll
    for (int e = 0; e < 8; ++e)
      frag[e] = __float2bfloat16(W[(size_t)(kbase + e) * nc + cb + lrow]);
    *(uint4*)&Wcs[(size_t)tid * 8] = *(uint4*)frag;
  } else if (tid < NWc + NX) {
    int u = tid - NWc;
    int l = u / (NCOLS * 64), r = u % (NCOLS * 64);
    int c = r >> 6, k0 = (r & 63) * 8;
    const float* W; int nc, cc;
    if (c < 512)       { W = aw.W[l*4+0]; nc = 512; cc = c;        }
    else if (c < 768)  { W = aw.W[l*4+1]; nc = 256; cc = c - 512;  }
    else if (c < 1280) { W = aw.W[l*4+2]; nc = 512; cc = c - 768;  }
    else               { W = aw.W[l*4+3]; nc = 256; cc = c - 1280; }
    __hip_bfloat16 frag[8];
#pragma unroll
    for (int e = 0; e < 8; ++e)
      frag[e] = __float2bfloat16(W[(size_t)(k0 + e) * nc + cc]);
    *(uint4*)&WxT[((size_t)l * NCOLS + c) * 512 + k0] = *(uint4*)frag;
  } else if (tid < NWc + NX + 2 * NCOLS) {
    int c = tid - NWc - NX;
    int l = c / NCOLS, cc = c % NCOLS;
    const float* b; int off;
    if (cc < 512)       { b = aw.b[l*4+0]; off = cc;        }
    else if (cc < 768)  { b = aw.b[l*4+1]; off = cc - 512;  }
    else if (cc < 1280) { b = aw.b[l*4+2]; off = cc - 768;  }
    else                { b = aw.b[l*4+3]; off = cc - 1280; }
    biasAll[c] = b[off];
  }
}

// ---------------------------------------------------------------- embed gather
__global__ void embed_gather(const int* __restrict__ seq, const float* __restrict__ emb,
                             __hip_bfloat16* __restrict__ X0) {
  int i = blockIdx.x * blockDim.x + threadIdx.x;
  int row = i >> 7, c4 = (i & 127) * 4;
  int idx = seq[row];
  float4 v = *(const float4*)&emb[(size_t)idx * HID + c4];
  union { __hip_bfloat16 h[4]; uint2 u; } pk;
  pk.h[0] = __float2bfloat16(v.x);
  pk.h[1] = __float2bfloat16(v.y);
  pk.h[2] = __float2bfloat16(v.z);
  pk.h[3] = __float2bfloat16(v.w);
  *(uint2*)&X0[(size_t)row * HID + c4] = pk.u;
}

// ---------------------------------------------------------------- P0 = X0 @ WxT^T + bias
__global__ __launch_bounds__(256) void gemm_p(const __hip_bfloat16* __restrict__ A,
                                              const __hip_bfloat16* __restrict__ WT,
                                              const float* __restrict__ bias,
                                              float* __restrict__ Psw) {
  const int tid = threadIdx.x;
  const int lane = tid & 63, w = tid >> 6;
  const int lrow = lane & 15, lgrp = lane >> 4;
  const int n0 = blockIdx.x * 64, m0 = blockIdx.y * 64;
  const int wm = w & 1, wn = w >> 1;
  __shared__ __hip_bfloat16 As[64][72];
  f32x4 acc[2][2];
#pragma unroll
  for (int a = 0; a < 2; ++a)
#pragma unroll
    for (int b = 0; b < 2; ++b) acc[a][b] = (f32x4){0.f, 0.f, 0.f, 0.f};

  const int lr = tid >> 2, lc = (tid & 3) * 16;
  for (int k0 = 0; k0 < 512; k0 += 64) {
    *(uint4*)&As[lr][lc]     = *(const uint4*)&A[((size_t)m0 + lr) * 512 + k0 + lc];
    *(uint4*)&As[lr][lc + 8] = *(const uint4*)&A[((size_t)m0 + lr) * 512 + k0 + lc + 8];
    __syncthreads();
#pragma unroll
    for (int kt = 0; kt < 2; ++kt) {
      bf16x8 a0 = *(const bf16x8*)&As[wm * 32 + lrow][kt * 32 + lgrp * 8];
      bf16x8 a1 = *(const bf16x8*)&As[wm * 32 + 16 + lrow][kt * 32 + lgrp * 8];
      bf16x8 b0 = *(const bf16x8*)&WT[((size_t)n0 + wn * 32 + lrow) * 512 + k0 + kt * 32 + lgrp * 8];
      bf16x8 b1 = *(const bf16x8*)&WT[((size_t)n0 + wn * 32 + 16 + lrow) * 512 + k0 + kt * 32 + lgrp * 8];
      acc[0][0] = mfma16(a0, b0, acc[0][0]);
      acc[0][1] = mfma16(a0, b1, acc[0][1]);
      acc[1][0] = mfma16(a1, b0, acc[1][0]);
      acc[1][1] = mfma16(a1, b1, acc[1][1]);
    }
    __syncthreads();
  }
  const int t = m0 >> 6;
#pragma unroll
  for (int mt = 0; mt < 2; ++mt) {
    int g = wm * 2 + mt;
#pragma unroll
    for (int nt = 0; nt < 2; ++nt) {
      int colb = n0 + wn * 32 + nt * 16; // wave-uniform
      int slot, wt;
      if (colb < 512)       { int c = colb;        wt = (c & 255) >> 5; slot = (c >> 8) * 2 + ((c >> 4) & 1); }
      else if (colb < 768)  { int c = colb - 512;  wt = c >> 5;         slot = 4 + ((c >> 4) & 1); }
      else if (colb < 1280) { int c = colb - 768;  wt = (c & 255) >> 5; slot = 6 + (c >> 8) * 2 + ((c >> 4) & 1); }
      else                  { int c = colb - 1280; wt = c >> 5;         slot = 10 + ((c >> 4) & 1); }
      float bv = bias[colb + lrow];
      float4 v;
      v.x = acc[mt][nt][0] + bv;
      v.y = acc[mt][nt][1] + bv;
      v.z = acc[mt][nt][2] + bv;
      v.w = acc[mt][nt][3] + bv;
      size_t off = (((size_t)g * 256 + t) * 12 + slot) * PSLOT + (size_t)wt * 256 + (size_t)lane * 4;
      *(float4*)&Psw[off] = v;
    }
  }
}

// ---------------------------------------------------------------- fused pipeline
// blocks 0-7  : layer-0 recurrence, col-split j=bid   (96KB weights in LDS)
// blocks 8-15 : layer-1 recurrence, col-split j=bid-8
// blocks 16-39: P1 helpers (read h0 frags from exchange ring)
struct SharedMem {
  union {
    struct {
      __hip_bfloat16 Wl[WG_FRAGS * 8];  // 96KB weight slice
      __hip_bfloat16 Ab[XBUF];          // 32KB stage A-fragment buffer
      __hip_bfloat16 st[2048];          // 4KB exchange staging (frag layout, own j slice)
      float zl[2048];                   // [64][32] z values
      float h1s[2048];                  // [64][32] own-col h1 (f32 master copy)
      float h2s[2048];                  // [64][32] own-col h2
    } rec;                              // 156KB
    struct {
      __hip_bfloat16 Bs[64][520];       // 66.5KB Wx slice
      __hip_bfloat16 As[2 * XBUF];      // 64KB h0 frags (h1|h2)
      float bias[64];
    } hlp;
  };
};

template <int LAYER>
__device__ __forceinline__ const float* paddr(const float* Pb, int g4, int t,
                                              int slot, int j, int lane) {
  size_t tt = LAYER ? (size_t)(t & (RING_D - 1)) : (size_t)t;
  size_t TD = LAYER ? RING_D : 256;
  return Pb + (((size_t)g4 * TD + tt) * 12 + slot) * PSLOT + (size_t)j * 256 +
         (size_t)lane * 4;
}

// stage Ab fill: frag f = q*512 + tid (lane-contiguous 16B ds_write, no conflicts)
#define AB_FILL(srcbuf)                                                      \
  {                                                                          \
    const char* sp = (const char*)(srcbuf) + (size_t)tid * 16;               \
    bf16x8 t0 = coh_frag(sp);                                                \
    bf16x8 t1 = coh_frag(sp + 8192);                                         \
    bf16x8 t2 = coh_frag(sp + 16384);                                        \
    bf16x8 t3 = coh_frag(sp + 24576);                                        \
    *(bf16x8*)&Ab[((size_t)0 * 512 + tid) * 8] = t0;                         \
    *(bf16x8*)&Ab[((size_t)1 * 512 + tid) * 8] = t1;                         \
    *(bf16x8*)&Ab[((size_t)2 * 512 + tid) * 8] = t2;                         \
    *(bf16x8*)&Ab[((size_t)3 * 512 + tid) * 8] = t3;                         \
  }

template <int LAYER>
__device__ void rec_body(const __hip_bfloat16* __restrict__ Wcs_j,
                         const float* __restrict__ Pbase,  // L0: Psw0; L1: P1 ring
                         __hip_bfloat16* __restrict__ R,   // exchange ring area
                         float* __restrict__ out,
                         uint32_t* __restrict__ flags,
                         SharedMem& sm, int j) {
  const int tid = threadIdx.x;
  const int lane = tid & 63, w = tid >> 6;      // 8 waves
  const int lrow = lane & 15, lgrp = lane >> 4;

  uint32_t* F = flags + LAYER * 1024;           // f[s][t] = F[s*256+t]
  uint32_t* cnt1 = flags + 2048;
  uint32_t* l1prog = flags + 2304;

  __hip_bfloat16* const Wl = sm.rec.Wl;
  __hip_bfloat16* const Ab = sm.rec.Ab;
  __hip_bfloat16* const st = sm.rec.st;
  float* const zl  = sm.rec.zl;
  float* const h1s = sm.rec.h1s;
  float* const h2s = sm.rec.h2s;

  const int HM = LAYER ? 1 : 7;                 // h ring mask (depth 2 / 8)
  __hip_bfloat16* const h1r = R + (size_t)(LAYER ? 20 : 0)  * XBUF;
  __hip_bfloat16* const h2r = R + (size_t)(LAYER ? 22 : 8)  * XBUF;
  __hip_bfloat16* const ag1 = R + (size_t)(LAYER ? 24 : 16) * XBUF;
  __hip_bfloat16* const ag2 = R + (size_t)(LAYER ? 26 : 18) * XBUF;

  // one-time init: weights -> LDS, h slices -> 0, saved page 0 -> 0
  for (int i = tid; i < WG_FRAGS; i += 512)
    *(bf16x8*)&Wl[(size_t)i * 8] = *(const bf16x8*)&Wcs_j[(size_t)i * 8];
  for (int i = tid; i < 2048; i += 512) { h1s[i] = 0.f; h2s[i] = 0.f; }
  if (LAYER == 1)
    for (int i = tid; i < 64 * 32; i += 512) {
      int row = i >> 5, c = 32 * j + (i & 31);
      if (c < SLICE_N) out[SAVED_OFF + (size_t)row * SLICE_N + c] = 0.f;
    }
  __syncthreads();

  // stage-1/3 wave constants: ct13 0,1 = z-tiles, 2,3 = r-tiles; 2 row-tiles
  const int ct13 = w >> 1, a0 = (w & 1) * 2, a1 = a0 + 1;
  const int cl13 = 16 * (ct13 & 1) + lrow;
  const int lt13 = (lgrp * 4) | ((cl13 >> 3) << 4);
  const int el13 = cl13 & 7;
  // stage-2/4 wave constants: ct24 0,1 g-tiles; a24 row-tile
  const int ct24 = w >> 2, a24 = w & 3;
  const int cl24 = 16 * ct24 + lrow;
  const int lt24 = (lgrp * 4) | ((cl24 >> 3) << 4);
  const int el24 = cl24 & 7;
  const int col24 = 32 * j + cl24;
  const int row24 = a24 * 16 + lgrp * 4;
  // publish word constants: lane -> (word row, el-half)
  const int pu = lane >> 1, phf = (lane & 1) * 4;
  const int plt13 = (ct13 & 1) * 32 + pu;   // stage-1/3 word row
  const int plt24 = ct24 * 32 + pu;         // stage-2/4 word row

  const float Q23 = 8388608.f, IQ23 = 1.f / 8388608.f;
  const float Q10 = 1024.f,    IQ10 = 1.f / 1024.f;

  float hr1[4] = {0.f, 0.f, 0.f, 0.f};
  float hr2[4] = {0.f, 0.f, 0.f, 0.f};

  for (int t = 0; t < T_STEPS; ++t) {
    // per-step P loads: all 6 float4 hoisted to step top (exposed once, not 4x)
    auto LDP = [&](int g, int slot) -> float4 {
      const float* a = paddr<LAYER>(Pbase, g, t, slot, j, lane);
      if (LAYER == 1) return coh_f4(a);       // ring reuse -> must bypass caches
      return *(const float4*)a;
    };
    float4 P_s1_0, P_s1_1, P_s2, P_s3_0, P_s3_1, P_s4;
    if (LAYER == 0) {                          // independent of flags: overlap poll
      P_s1_0 = LDP(a0, ct13);      P_s1_1 = LDP(a1, ct13);
      P_s2   = LDP(a24, 4 + ct24);
      P_s3_0 = LDP(a0, 6 + ct13);  P_s3_1 = LDP(a1, 6 + ct13);
      P_s4   = LDP(a24, 10 + ct24);
    }

    // ================== stage 1: zr1 = sigma(P + h2 @ Uzr1)
    if (tid == 0) {
      if (LAYER == 1) { POLLGE(&cnt1[t], NHELP); }
      if (t > 0)      { POLLGE(&F[3 * 256 + t - 1], 8); }
    }
    __syncthreads();
    if (LAYER == 1) {
      P_s1_0 = LDP(a0, ct13);      P_s1_1 = LDP(a1, ct13);
      P_s2   = LDP(a24, 4 + ct24);
      P_s3_0 = LDP(a0, 6 + ct13);  P_s3_1 = LDP(a1, 6 + ct13);
      P_s4   = LDP(a24, 10 + ct24);
    }
    if (t == 0) {
      bf16x8 zz = {0, 0, 0, 0, 0, 0, 0, 0};
#pragma unroll
      for (int q = 0; q < 4; ++q) *(bf16x8*)&Ab[((size_t)q * 512 + tid) * 8] = zz;
    } else {
      AB_FILL(&h2r[(size_t)((t - 1) & HM) * XBUF]);
    }
    __syncthreads();
    {
      f32x4 c0 = (f32x4){0.f, 0.f, 0.f, 0.f}, c1 = c0;
#pragma unroll
      for (int kt = 0; kt < 8; ++kt) {
        bf16x8 A0 = *(const bf16x8*)&Ab[((a0 * 8 + kt) * 64 + lane) * 8];
        bf16x8 A1 = *(const bf16x8*)&Ab[((a1 * 8 + kt) * 64 + lane) * 8];
        bf16x8 B  = *(const bf16x8*)&Wl[((ct13 * 8 + kt) * 64 + lane) * 8];
        c0 = mfma16(A0, B, c0);
        c1 = mfma16(A1, B, c1);
      }
      if (ct13 < 2) {
#pragma unroll
        for (int rr = 0; rr < 4; ++rr) {
          zl[(a0 * 16 + lgrp * 4 + rr) * 32 + cl13] = 0.875f * sigm_f(c0[rr] + P_s1_0[rr]) + 0.125f;
          zl[(a1 * 16 + lgrp * 4 + rr) * 32 + cl13] = 0.875f * sigm_f(c1[rr] + P_s1_1[rr]) + 0.125f;
        }
      } else {
#pragma unroll
        for (int rr = 0; rr < 4; ++rr) {
          float r0 = sigm_f(c0[rr] + P_s1_0[rr]);
          float r1 = sigm_f(c1[rr] + P_s1_1[rr]);
          st[(a0 * 64 + lt13 + rr) * 8 + el13] =
              __float2bfloat16(r0 * h2s[(a0 * 16 + lgrp * 4 + rr) * 32 + cl13]);
          st[(a1 * 64 + lt13 + rr) * 8 + el13] =
              __float2bfloat16(r1 * h2s[(a1 * 16 + lgrp * 4 + rr) * 32 + cl13]);
        }
        CFENCE();   // DS in-order per wave: readback below sees writes above
        __hip_bfloat16* dst = &ag1[(size_t)(t & 1) * XBUF];
        unsigned long long v0 = *(const unsigned long long*)&st[(a0 * 64 + plt13) * 8 + phf];
        unsigned long long v1 = *(const unsigned long long*)&st[(a1 * 64 + plt13) * 8 + phf];
        coh_store_u64(&dst[((size_t)(a0 * 8 + j) * 64 + plt13) * 8 + phf], v0);
        coh_store_u64(&dst[((size_t)(a1 * 8 + j) * 64 + plt13) * 8 + phf], v1);
      }
    }
    __syncthreads();   // drains DS + all waves' coh stores (vmcnt0) -> data at L3
    if (tid == 0)
      __hip_atomic_fetch_add(&F[0 * 256 + t], 1u, __ATOMIC_RELAXED, __HIP_MEMORY_SCOPE_AGENT);

    // ================== stage 2: g1 = tanh(P + ag1 @ Ug1); h1 update
    if (tid == 0) {
      POLLGE(&F[0 * 256 + t], 8);
      if (LAYER == 0 && t >= 8) { POLLGE(&cnt1[t - 8], NHELP); } // h-ring WAR vs helpers
    }
    __syncthreads();
    AB_FILL(&ag1[(size_t)(t & 1) * XBUF]);
    __syncthreads();
    {
      f32x4 c = (f32x4){0.f, 0.f, 0.f, 0.f};
#pragma unroll
      for (int kt = 0; kt < 8; ++kt) {
        bf16x8 A = *(const bf16x8*)&Ab[((a24 * 8 + kt) * 64 + lane) * 8];
        bf16x8 B = *(const bf16x8*)&Wl[((32 + ct24 * 8 + kt) * 64 + lane) * 8];
        c = mfma16(A, B, c);
      }
#pragma unroll
      for (int rr = 0; rr < 4; ++rr) {
        float gv = tanh_f(c[rr] + P_s2[rr]);
        float z  = zl[(row24 + rr) * 32 + cl24];
        float zq = floorf(z * Q10) * IQ10;
        float h = hr1[rr];
        h = floorf(h * zq * Q23) * IQ23;
        h = h + rintf((1.f - z) * gv * Q23) * IQ23;
        hr1[rr] = h;
        h1s[(row24 + rr) * 32 + cl24] = h;
        st[(a24 * 64 + lt24 + rr) * 8 + el24] = __float2bfloat16(h);
        int row = row24 + rr;
        if (LAYER == 1 && col24 < SLICE_N)
          out[SAVED_OFF + (size_t)(t + 1) * (BATCH * SLICE_N) + (size_t)row * SLICE_N + col24] = h;
        if (t == T_STEPS - 1)
          out[(size_t)LAYER * (BATCH * HID) + (size_t)row * HID + col24] = h;
      }
      CFENCE();
      __hip_bfloat16* dst = &h1r[(size_t)(t & HM) * XBUF];
      unsigned long long v = *(const unsigned long long*)&st[(a24 * 64 + plt24) * 8 + phf];
      coh_store_u64(&dst[((size_t)(a24 * 8 + j) * 64 + plt24) * 8 + phf], v);
    }
    __syncthreads();
    if (tid == 0)
      __hip_atomic_fetch_add(&F[1 * 256 + t], 1u, __ATOMIC_RELAXED, __HIP_MEMORY_SCOPE_AGENT);

    // ================== stage 3: zr2 = sigma(P + h1 @ Uzr2)
    if (tid == 0) { POLLGE(&F[1 * 256 + t], 8); }
    __syncthreads();
    AB_FILL(&h1r[(size_t)(t & HM) * XBUF]);
    __syncthreads();
    {
      f32x4 c0 = (f32x4){0.f, 0.f, 0.f, 0.f}, c1 = c0;
#pragma unroll
      for (int kt = 0; kt < 8; ++kt) {
        bf16x8 A0 = *(const bf16x8*)&Ab[((a0 * 8 + kt) * 64 + lane) * 8];
        bf16x8 A1 = *(const bf16x8*)&Ab[((a1 * 8 + kt) * 64 + lane) * 8];
        bf16x8 B  = *(const bf16x8*)&Wl[((48 + ct13 * 8 + kt) * 64 + lane) * 8];
        c0 = mfma16(A0, B, c0);
        c1 = mfma16(A1, B, c1);
      }
      if (ct13 < 2) {
#pragma unroll
        for (int rr = 0; rr < 4; ++rr) {
          zl[(a0 * 16 + lgrp * 4 + rr) * 32 + cl13] = 0.875f * sigm_f(c0[rr] + P_s3_0[rr]) + 0.125f;
          zl[(a1 * 16 + lgrp * 4 + rr) * 32 + cl13] = 0.875f * sigm_f(c1[rr] + P_s3_1[rr]) + 0.125f;
        }
      } else {
#pragma unroll
        for (int rr = 0; rr < 4; ++rr) {
          float r0 = sigm_f(c0[rr] + P_s3_0[rr]);
          float r1 = sigm_f(c1[rr] + P_s3_1[rr]);
          st[(a0 * 64 + lt13 + rr) * 8 + el13] =
              __float2bfloat16(r0 * h1s[(a0 * 16 + lgrp * 4 + rr) * 32 + cl13]);
          st[(a1 * 64 + lt13 + rr) * 8 + el13] =
              __float2bfloat16(r1 * h1s[(a1 * 16 + lgrp * 4 + rr) * 32 + cl13]);
        }
        CFENCE();
        __hip_bfloat16* dst = &ag2[(size_t)(t & 1) * XBUF];
        unsigned long long v0 = *(const unsigned long long*)&st[(a0 * 64 + plt13) * 8 + phf];
        unsigned long long v1 = *(const unsigned long long*)&st[(a1 * 64 + plt13) * 8 + phf];
        coh_store_u64(&dst[((size_t)(a0 * 8 + j) * 64 + plt13) * 8 + phf], v0);
        coh_store_u64(&dst[((size_t)(a1 * 8 + j) * 64 + plt13) * 8 + phf], v1);
      }
    }
    __syncthreads();
    if (tid == 0)
      __hip_atomic_fetch_add(&F[2 * 256 + t], 1u, __ATOMIC_RELAXED, __HIP_MEMORY_SCOPE_AGENT);

    // ================== stage 4: g2 = tanh(P + ag2 @ Ug2); h2 update
    if (tid == 0) { POLLGE(&F[2 * 256 + t], 8); }
    __syncthreads();
    AB_FILL(&ag2[(size_t)(t & 1) * XBUF]);
    __syncthreads();
    {
      f32x4 c = (f32x4){0.f, 0.f, 0.f, 0.f};
#pragma unroll
      for (int kt = 0; kt < 8; ++kt) {
        bf16x8 A = *(const bf16x8*)&Ab[((a24 * 8 + kt) * 64 + lane) * 8];
        bf16x8 B = *(const bf16x8*)&Wl[((80 + ct24 * 8 + kt) * 64 + lane) * 8];
        c = mfma16(A, B, c);
      }
#pragma unroll
      for (int rr = 0; rr < 4; ++rr) {
        float gv = tanh_f(c[rr] + P_s4[rr]);
        float z  = zl[(row24 + rr) * 32 + cl24];
        float zq = floorf(z * Q10) * IQ10;
        float h = hr2[rr];
        h = floorf(h * zq * Q23) * IQ23;
        h = h + rintf((1.f - z) * gv * Q23) * IQ23;
        hr2[rr] = h;
        h2s[(row24 + rr) * 32 + cl24] = h;
        st[(a24 * 64 + lt24 + rr) * 8 + el24] = __float2bfloat16(h);
        int row = row24 + rr;
        if (t == T_STEPS - 1)
          out[(size_t)LAYER * (BATCH * HID) + (size_t)row * HID + HALF + col24] = h;
      }
      CFENCE();
      __hip_bfloat16* dst = &h2r[(size_t)(t & HM) * XBUF];
      unsigned long long v = *(const unsigned long long*)&st[(a24 * 64 + plt24) * 8 + phf];
      coh_store_u64(&dst[((size_t)(a24 * 8 + j) * 64 + plt24) * 8 + phf], v);
    }
    __syncthreads();
    if (tid == 0) {
      __hip_atomic_fetch_add(&F[3 * 256 + t], 1u, __ATOMIC_RELAXED, __HIP_MEMORY_SCOPE_AGENT);
      if (LAYER == 1)
        __hip_atomic_store(&l1prog[j], (uint32_t)(t + 1), __ATOMIC_RELAXED, __HIP_MEMORY_SCOPE_AGENT);
    }
  }
}

// helper: P1(t)[:, n0:n0+64] = h0(t) @ Wx1-slice + bias. A-frags come from the
// layer-0 h exchange ring (identical bf16 values / K-order as before).
__device__ void helper_body(const __hip_bfloat16* __restrict__ WxT1,
                            const float* __restrict__ bias1,
                            const __hip_bfloat16* __restrict__ R,
                            float* __restrict__ P1ring,
                            uint32_t* __restrict__ flags,
                            SharedMem& sm, int n) {
  const int tid = threadIdx.x;
  const int lane = tid & 63, w = tid >> 6;
  const int lrow = lane & 15, lgrp = lane >> 4;
  const int n0 = n * 64;

  uint32_t* F0 = flags;                  // layer-0 stage flags
  uint32_t* cnt1 = flags + 2048;
  uint32_t* l1prog = flags + 2304;
  const __hip_bfloat16* h1r = R;         // L0 h rings (depth 8)
  const __hip_bfloat16* h2r = R + (size_t)8 * XBUF;

  for (int i = tid; i < 64 * 64; i += 512) {
    int c = i >> 6, k8 = (i & 63) * 8;
    *(bf16x8*)&sm.hlp.Bs[c][k8] = *(const bf16x8*)&WxT1[(size_t)(n0 + c) * 512 + k8];
  }
  if (tid < 64) sm.hlp.bias[tid] = bias1[n0 + tid];
  __syncthreads();

  const int mt = w & 3, chb = (w >> 2) * 2;   // row-tile, col-subtile pair

  for (int t = 0; t < T_STEPS; ++t) {
    if (tid == 0) {
      POLLGE(&F0[3 * 256 + t], 8);            // h1,h2 of step t published
      if (t >= RING_D) {                      // P1-ring WAR vs layer-1
        for (;;) {
          uint32_t mm = 0xffffffffu;
#pragma unroll
          for (int q = 0; q < 8; ++q) {
            uint32_t v = __hip_atomic_load(&l1prog[q], __ATOMIC_RELAXED, __HIP_MEMORY_SCOPE_AGENT);
            mm = v < mm ? v : mm;
          }
          if (mm + (uint32_t)(RING_D - 1) >= (uint32_t)t) break;
          __builtin_amdgcn_s_sleep(1);
        }
      }
    }
    __syncthreads();
    {
      const char* s1 = (const char*)&h1r[(size_t)(t & 7) * XBUF] + (size_t)tid * 16;
      const char* s2 = (const char*)&h2r[(size_t)(t & 7) * XBUF] + (size_t)tid * 16;
      bf16x8 tA[8];
#pragma unroll
      for (int k = 0; k < 4; ++k) tA[k] = coh_frag(s1 + (size_t)k * 8192);
#pragma unroll
      for (int k = 4; k < 8; ++k) tA[k] = coh_frag(s2 + (size_t)(k - 4) * 8192);
#pragma unroll
      for (int k = 0; k < 8; ++k) *(bf16x8*)&sm.hlp.As[(size_t)(k * 512 + tid) * 8] = tA[k];
    }
    __syncthreads();
#pragma unroll
    for (int q = 0; q < 2; ++q) {
      int ch = chb + q;
      f32x4 c = (f32x4){0.f, 0.f, 0.f, 0.f};
#pragma unroll
      for (int kt = 0; kt < 16; ++kt) {
        const bf16x8 A = *(const bf16x8*)&sm.hlp.As[
            kt < 8 ? (size_t)((mt * 8 + kt) * 64 + lane) * 8
                   : (size_t)XBUF + (size_t)((mt * 8 + (kt - 8)) * 64 + lane) * 8];
        const bf16x8 B = *(const bf16x8*)&sm.hlp.Bs[ch * 16 + lrow][kt * 32 + lgrp * 8];
        c = mfma16(A, B, c);
      }
      int colb = n0 + ch * 16;               // wave-uniform
      int slot, wt;
      if (colb < 512)       { int cc = colb;        wt = (cc & 255) >> 5; slot = (cc >> 8) * 2 + ((cc >> 4) & 1); }
      else if (colb < 768)  { int cc = colb - 512;  wt = cc >> 5;         slot = 4 + ((cc >> 4) & 1); }
      else if (colb < 1280) { int cc = colb - 768;  wt = (cc & 255) >> 5; slot = 6 + (cc >> 8) * 2 + ((cc >> 4) & 1); }
      else                  { int cc = colb - 1280; wt = cc >> 5;         slot = 10 + ((cc >> 4) & 1); }
      float bv = sm.hlp.bias[ch * 16 + lrow];
      union { float4 f; unsigned long long u[2]; } uv;
      uv.f.x = c[0] + bv; uv.f.y = c[1] + bv; uv.f.z = c[2] + bv; uv.f.w = c[3] + bv;
      size_t off = (((size_t)mt * RING_D + (t & (RING_D - 1))) * 12 + slot) * PSLOT +
                   (size_t)wt * 256 + (size_t)lane * 4;
      unsigned long long* d = (unsigned long long*)&P1ring[off];
      coh_store_u64(d, uv.u[0]);
      coh_store_u64(d + 1, uv.u[1]);
    }
    __syncthreads();   // drains vmcnt: all coherent stores visible at L3
    if (tid == 0)
      __hip_atomic_fetch_add(&cnt1[t], 1u, __ATOMIC_RELAXED, __HIP_MEMORY_SCOPE_AGENT);
  }
}

__global__ __attribute__((amdgpu_waves_per_eu(2))) __launch_bounds__(512)
void fused_kernel(const __hip_bfloat16* __restrict__ Wcs,
                  const float* __restrict__ Psw0,
                  float* __restrict__ P1ring,
                  const __hip_bfloat16* __restrict__ WxT1,
                  const float* __restrict__ bias1,
                  float* __restrict__ out,
                  __hip_bfloat16* __restrict__ R,
                  uint32_t* __restrict__ flags) {
  __shared__ SharedMem sm;
  const int bid = blockIdx.x;
  if (bid < 8)
    rec_body<0>(Wcs + (size_t)bid * WG_FRAGS * 8, Psw0, R, out, flags, sm, bid);
  else if (bid < 16)
    rec_body<1>(Wcs + (size_t)(8 + (bid - 8)) * WG_FRAGS * 8, P1ring, R, out, flags, sm, bid - 8);
  else
    helper_body(WxT1, bias1, R, P1ring, flags, sm, bid - 16);
}

// ---------------------------------------------------------------- launch
extern "C" void kernel_launch(void* const* d_in, const int* in_sizes, int n_in,
                              void* d_out, int out_size, void* d_ws, size_t ws_size,
                              hipStream_t stream) {
  const int*   seq = (const int*)d_in[0];
  const float* emb = (const float*)d_in[1];
  AllW aw;
  for (int l = 0; l < 2; ++l)
    for (int s = 0; s < 4; ++s) {
      aw.W[l * 4 + s] = (const float*)d_in[2 + l * 8 + s * 2];
      aw.b[l * 4 + s] = (const float*)d_in[2 + l * 8 + s * 2 + 1];
    }

  uint8_t* wp = (uint8_t*)d_ws;
  float* Psw = (float*)wp;                   wp += (size_t)4 * 256 * PSTEP * 4;        // 100.7 MB (P0)
  __hip_bfloat16* X0 = (__hip_bfloat16*)wp;  wp += (size_t)MROWS * HID * 2;            // 16.8 MB (X0 -> P1 ring)
  __hip_bfloat16* R  = (__hip_bfloat16*)wp;  wp += (size_t)MROWS * HID * 2;            // 16.8 MB (exchange rings)
  __hip_bfloat16* Wcs = (__hip_bfloat16*)wp; wp += (size_t)2 * 8 * WG_FRAGS * 8 * 2;   // 1.6 MB
  __hip_bfloat16* WxT = (__hip_bfloat16*)wp; wp += (size_t)2 * NCOLS * 512 * 2;        // 3.1 MB
  float* biasAll = (float*)wp;               wp += (size_t)2 * NCOLS * 4;
  uint32_t* flags = (uint32_t*)wp;           wp += 16384;   // f[2][4][256] | cnt1[256] | l1prog[8]

  float* out = (float*)d_out;

  const int prepTot = 2 * 8 * WG_FRAGS + 2 * NCOLS * 64 + 2 * NCOLS;
  const int prepN = (prepTot + 255) / 256;
  prep_weights<<<prepN, 256, 0, stream>>>(aw, Wcs, WxT, biasAll, flags);
  embed_gather<<<(MROWS * 128) / 256, 256, 0, stream>>>(seq, emb, X0);

  gemm_p<<<dim3(24, 256), 256, 0, stream>>>(X0, WxT, biasAll, Psw);
  // X0 dead after gemm_p -> reuse as P1 ring (32 steps deep)
  fused_kernel<<<8 + 8 + NHELP, 512, 0, stream>>>(
      Wcs, Psw, (float*)X0, WxT + (size_t)NCOLS * 512, biasAll + NCOLS,
      out, R, flags);
}

// Round 9
// 2504.520 us; speedup vs baseline: 1.5651x; 1.2100x over previous
//
#include <hip/hip_runtime.h>
#include <hip/hip_bf16.h>
#include <stdint.h>

#define T_STEPS 256
#define BATCH   64
#define HID     512
#define HALF    256
#define NCOLS   1536              // [zr1:512 | g1:256 | zr2:512 | g2:256]
#define MROWS   (T_STEPS * BATCH) // 16384
#define SLICE_N 100
#define SAVED_OFF (2 * BATCH * HID) // 65536 floats into d_out

// P layout: [g4][t][slot:12][wt:8][lane:64][rr:4] f32
#define PSLOT 2048              // 8*64*4 floats
#define PSTEP (12 * PSLOT)      // floats per (g4, t)

#define RING_D 32               // P1 ring depth (timesteps); lives in dead X0
#define NHELP 24                // helper WGs = 1536/64 column tiles

// col-split recurrence: 8 WGs per layer, weights LDS-resident (96KB/WG).
// Exchange buffers (global, A-fragment order): elem (row,k) at
// ((a*8+kt)*64 + ((row&15)|(((k&31)>>3)<<4)))*8 + (k&7), a=row>>4, kt=k>>5.
#define XBUF 16384              // bf16 elems per exchange buffer (32KB)
#define WG_FRAGS 6144           // 16B frags per (layer,j) weight slice (96KB)

typedef short bf16x8 __attribute__((ext_vector_type(8)));
typedef float f32x4  __attribute__((ext_vector_type(4)));

__device__ __forceinline__ f32x4 mfma16(bf16x8 a, bf16x8 b, f32x4 c) {
  return __builtin_amdgcn_mfma_f32_16x16x32_bf16(a, b, c, 0, 0, 0);
}
__device__ __forceinline__ float sigm_f(float x) {
  return __builtin_amdgcn_rcpf(1.f + __expf(-x));
}
__device__ __forceinline__ float tanh_f(float x) {
  x = fminf(fmaxf(x, -30.f), 30.f);
  float e = __expf(-2.f * x);
  return (1.f - e) * __builtin_amdgcn_rcpf(1.f + e);
}

// ---- L3 (agent) coherent ops: proven path (rounds 5-8) -------------------
__device__ __forceinline__ unsigned long long coh_u64(const void* p) {
  return __hip_atomic_load((const unsigned long long*)p, __ATOMIC_RELAXED,
                           __HIP_MEMORY_SCOPE_AGENT);
}
__device__ __forceinline__ void coh_store_u64(void* p, unsigned long long v) {
  __hip_atomic_store((unsigned long long*)p, v, __ATOMIC_RELAXED,
                     __HIP_MEMORY_SCOPE_AGENT);
}
__device__ __forceinline__ bf16x8 coh_frag(const void* p) {
  union { unsigned long long u[2]; bf16x8 v; } x;
  x.u[0] = coh_u64(p);
  x.u[1] = coh_u64((const char*)p + 8);
  return x.v;
}
__device__ __forceinline__ float4 coh_f4(const void* p) {
  union { unsigned long long u[2]; float4 v; } x;
  x.u[0] = coh_u64(p);
  x.u[1] = coh_u64((const char*)p + 8);
  return x.v;
}

#define POLLGE(addr, val)                                                        \
  while (__hip_atomic_load((addr), __ATOMIC_RELAXED, __HIP_MEMORY_SCOPE_AGENT) < \
         (uint32_t)(val))                                                        \
    __builtin_amdgcn_s_sleep(1);

// ---- XCD-local (L2) ops: fast mode only, gated on verified colocation ----
// Flag atomics without sc1 execute at the XCD-local L2 (GCN atomics run in L2).
// Data: plain stores (L1 write-through -> L2); reads after buffer_inv sc0
// (L1-only invalidate; does NOT touch L2 -- unlike the agent acquire fence).
__device__ __forceinline__ void l2_flag_add(uint32_t* p) {
  uint32_t one = 1u;
  asm volatile("global_atomic_add %0, %1, off" :: "v"(p), "v"(one) : "memory");
}
__device__ __forceinline__ uint32_t l2_flag_read(uint32_t* p) {
  uint32_t r, zero = 0u;
  asm volatile("global_atomic_add %0, %1, %2, off sc0\n\t"
               "s_waitcnt vmcnt(0)"
               : "=&v"(r) : "v"(p), "v"(zero) : "memory");
  return r;
}
#define L2POLLGE(addr, val)                                                  \
  while (l2_flag_read(addr) < (uint32_t)(val)) __builtin_amdgcn_s_sleep(1);
__device__ __forceinline__ void l1_inv() {
  asm volatile("buffer_inv sc0\n\ts_waitcnt vmcnt(0)" ::: "memory");
}

// compiler reorder fence (no codegen); HW DS pipe is in-order per wave
#define CFENCE() asm volatile("" ::: "memory")

struct AllW {
  const float* W[8]; // l0: zr1,g1,zr2,g2 ; l1: zr1,g1,zr2,g2
  const float* b[8];
};

// ---------------------------------------------------------------- prep
// Wcs: [l][j][g:96][lane:64] 16B frags. g<32: zr1 (ct=g>>3, kt=g&7);
// 32..47: g1; 48..79: zr2; 80..95: g2. zr ct<2 -> z cols 32j+16ct,
// zr ct>=2 -> r cols 256+32j+16(ct-2); g: cols 32j+16ct.
__global__ void prep_weights(AllW aw, __hip_bfloat16* __restrict__ Wcs,
                             __hip_bfloat16* __restrict__ WxT,
                             float* __restrict__ biasAll,
                             uint32_t* __restrict__ flags) {
  int tid = blockIdx.x * blockDim.x + threadIdx.x;
  if (tid < 8192) flags[tid] = 0u;   // zero all sync flags every launch
  const int NWc = 2 * 8 * WG_FRAGS;  // 98304
  const int NX = 2 * NCOLS * 64;
  if (tid < NWc) {
    int l = tid / (8 * WG_FRAGS), r = tid % (8 * WG_FRAGS);
    int j = r / WG_FRAGS, r2 = r % WG_FRAGS;
    int g = r2 >> 6, lane = r2 & 63;
    int lrow = lane & 15, lgrp = lane >> 4;
    int s, gg;
    if (g < 32)      { s = 0; gg = g; }
    else if (g < 48) { s = 1; gg = g - 32; }
    else if (g < 80) { s = 2; gg = g - 48; }
    else             { s = 3; gg = g - 80; }
    int ct = gg >> 3, kt = gg & 7;
    int zr = (s == 0 || s == 2);
    int nc = zr ? 512 : 256;
    int cb = zr ? (ct < 2 ? 32 * j + 16 * ct : 256 + 32 * j + 16 * (ct - 2))
                : (32 * j + 16 * ct);
    const float* W = aw.W[l * 4 + s];
    int kbase = 512 + kt * 32 + lgrp * 8;
    __hip_bfloat16 frag[8];
#pragma unroll
    for (int e = 0; e < 8; ++e)
      frag[e] = __float2bfloat16(W[(size_t)(kbase + e) * nc + cb + lrow]);
    *(uint4*)&Wcs[(size_t)tid * 8] = *(uint4*)frag;
  } else if (tid < NWc + NX) {
    int u = tid - NWc;
    int l = u / (NCOLS * 64), r = u % (NCOLS * 64);
    int c = r >> 6, k0 = (r & 63) * 8;
    const float* W; int nc, cc;
    if (c < 512)       { W = aw.W[l*4+0]; nc = 512; cc = c;        }
    else if (c < 768)  { W = aw.W[l*4+1]; nc = 256; cc = c - 512;  }
    else if (c < 1280) { W = aw.W[l*4+2]; nc = 512; cc = c - 768;  }
    else               { W = aw.W[l*4+3]; nc = 256; cc = c - 1280; }
    __hip_bfloat16 frag[8];
#pragma unroll
    for (int e = 0; e < 8; ++e)
      frag[e] = __float2bfloat16(W[(size_t)(k0 + e) * nc + cc]);
    *(uint4*)&WxT[((size_t)l * NCOLS + c) * 512 + k0] = *(uint4*)frag;
  } else if (tid < NWc + NX + 2 * NCOLS) {
    int c = tid - NWc - NX;
    int l = c / NCOLS, cc = c % NCOLS;
    const float* b; int off;
    if (cc < 512)       { b = aw.b[l*4+0]; off = cc;        }
    else if (cc < 768)  { b = aw.b[l*4+1]; off = cc - 512;  }
    else if (cc < 1280) { b = aw.b[l*4+2]; off = cc - 768;  }
    else                { b = aw.b[l*4+3]; off = cc - 1280; }
    biasAll[c] = b[off];
  }
}

// ---------------------------------------------------------------- embed gather
__global__ void embed_gather(const int* __restrict__ seq, const float* __restrict__ emb,
                             __hip_bfloat16* __restrict__ X0) {
  int i = blockIdx.x * blockDim.x + threadIdx.x;
  int row = i >> 7, c4 = (i & 127) * 4;
  int idx = seq[row];
  float4 v = *(const float4*)&emb[(size_t)idx * HID + c4];
  union { __hip_bfloat16 h[4]; uint2 u; } pk;
  pk.h[0] = __float2bfloat16(v.x);
  pk.h[1] = __float2bfloat16(v.y);
  pk.h[2] = __float2bfloat16(v.z);
  pk.h[3] = __float2bfloat16(v.w);
  *(uint2*)&X0[(size_t)row * HID + c4] = pk.u;
}

// ---------------------------------------------------------------- P0 = X0 @ WxT^T + bias
__global__ __launch_bounds__(256) void gemm_p(const __hip_bfloat16* __restrict__ A,
                                              const __hip_bfloat16* __restrict__ WT,
                                              const float* __restrict__ bias,
                                              float* __restrict__ Psw) {
  const int tid = threadIdx.x;
  const int lane = tid & 63, w = tid >> 6;
  const int lrow = lane & 15, lgrp = lane >> 4;
  const int n0 = blockIdx.x * 64, m0 = blockIdx.y * 64;
  const int wm = w & 1, wn = w >> 1;
  __shared__ __hip_bfloat16 As[64][72];
  f32x4 acc[2][2];
#pragma unroll
  for (int a = 0; a < 2; ++a)
#pragma unroll
    for (int b = 0; b < 2; ++b) acc[a][b] = (f32x4){0.f, 0.f, 0.f, 0.f};

  const int lr = tid >> 2, lc = (tid & 3) * 16;
  for (int k0 = 0; k0 < 512; k0 += 64) {
    *(uint4*)&As[lr][lc]     = *(const uint4*)&A[((size_t)m0 + lr) * 512 + k0 + lc];
    *(uint4*)&As[lr][lc + 8] = *(const uint4*)&A[((size_t)m0 + lr) * 512 + k0 + lc + 8];
    __syncthreads();
#pragma unroll
    for (int kt = 0; kt < 2; ++kt) {
      bf16x8 a0 = *(const bf16x8*)&As[wm * 32 + lrow][kt * 32 + lgrp * 8];
      bf16x8 a1 = *(const bf16x8*)&As[wm * 32 + 16 + lrow][kt * 32 + lgrp * 8];
      bf16x8 b0 = *(const bf16x8*)&WT[((size_t)n0 + wn * 32 + lrow) * 512 + k0 + kt * 32 + lgrp * 8];
      bf16x8 b1 = *(const bf16x8*)&WT[((size_t)n0 + wn * 32 + 16 + lrow) * 512 + k0 + kt * 32 + lgrp * 8];
      acc[0][0] = mfma16(a0, b0, acc[0][0]);
      acc[0][1] = mfma16(a0, b1, acc[0][1]);
      acc[1][0] = mfma16(a1, b0, acc[1][0]);
      acc[1][1] = mfma16(a1, b1, acc[1][1]);
    }
    __syncthreads();
  }
  const int t = m0 >> 6;
#pragma unroll
  for (int mt = 0; mt < 2; ++mt) {
    int g = wm * 2 + mt;
#pragma unroll
    for (int nt = 0; nt < 2; ++nt) {
      int colb = n0 + wn * 32 + nt * 16; // wave-uniform
      int slot, wt;
      if (colb < 512)       { int c = colb;        wt = (c & 255) >> 5; slot = (c >> 8) * 2 + ((c >> 4) & 1); }
      else if (colb < 768)  { int c = colb - 512;  wt = c >> 5;         slot = 4 + ((c >> 4) & 1); }
      else if (colb < 1280) { int c = colb - 768;  wt = (c & 255) >> 5; slot = 6 + (c >> 8) * 2 + ((c >> 4) & 1); }
      else                  { int c = colb - 1280; wt = c >> 5;         slot = 10 + ((c >> 4) & 1); }
      float bv = bias[colb + lrow];
      float4 v;
      v.x = acc[mt][nt][0] + bv;
      v.y = acc[mt][nt][1] + bv;
      v.z = acc[mt][nt][2] + bv;
      v.w = acc[mt][nt][3] + bv;
      size_t off = (((size_t)g * 256 + t) * 12 + slot) * PSLOT + (size_t)wt * 256 + (size_t)lane * 4;
      *(float4*)&Psw[off] = v;
    }
  }
}

// ---------------------------------------------------------------- fused pipeline
// 64 blocks; xslot=bid&7 (presumed XCD), idx=bid>>3:
//   xslot==0 -> layer-0 WG j=idx   (8 WGs, same XCD if mapping holds)
//   xslot==1 -> layer-1 WG j=idx
//   xslot>=2, idx<4 -> helper n=(xslot-2)*4+idx (24); else exit.
// Rec WGs verify colocation via HW_REG_XCC_ID rendezvous; fast (L2) exchange
// only if all 8 WGs of the layer share an XCD, else proven agent (L3) path.
struct SharedMem {
  union {
    struct {
      __hip_bfloat16 Wl[WG_FRAGS * 8];  // 96KB weight slice
      __hip_bfloat16 Ab[XBUF];          // 32KB stage A-fragment buffer
      __hip_bfloat16 st[2048];          // 4KB exchange staging (frag layout, own j slice)
      float zl[2048];                   // [64][32] z values
      float h1s[2048];                  // [64][32] own-col h1 (f32 master copy)
      float h2s[2048];                  // [64][32] own-col h2
      uint32_t fastf;                   // colocation verdict
    } rec;                              // ~156KB
    struct {
      __hip_bfloat16 Bs[64][520];       // 66.5KB Wx slice
      __hip_bfloat16 As[2 * XBUF];      // 64KB h0 frags (h1|h2)
      float bias[64];
    } hlp;
  };
};

template <int LAYER>
__device__ __forceinline__ const float* paddr(const float* Pb, int g4, int t,
                                              int slot, int j, int lane) {
  size_t tt = LAYER ? (size_t)(t & (RING_D - 1)) : (size_t)t;
  size_t TD = LAYER ? RING_D : 256;
  return Pb + (((size_t)g4 * TD + tt) * 12 + slot) * PSLOT + (size_t)j * 256 +
         (size_t)lane * 4;
}

// stage Ab fill: frag f = q*512 + tid (lane-contiguous 16B ds_write)
#define AB_FILL_ANY(srcbuf, FMF)                                             \
  {                                                                          \
    const char* sp_ = (const char*)(srcbuf) + (size_t)tid * 16;              \
    bf16x8 t0_, t1_, t2_, t3_;                                               \
    if (FMF) {                                                               \
      t0_ = *(const bf16x8*)(sp_);                                           \
      t1_ = *(const bf16x8*)(sp_ + 8192);                                    \
      t2_ = *(const bf16x8*)(sp_ + 16384);                                   \
      t3_ = *(const bf16x8*)(sp_ + 24576);                                   \
    } else {                                                                 \
      t0_ = coh_frag(sp_);                                                   \
      t1_ = coh_frag(sp_ + 8192);                                            \
      t2_ = coh_frag(sp_ + 16384);                                           \
      t3_ = coh_frag(sp_ + 24576);                                           \
    }                                                                        \
    *(bf16x8*)&Ab[((size_t)0 * 512 + tid) * 8] = t0_;                        \
    *(bf16x8*)&Ab[((size_t)1 * 512 + tid) * 8] = t1_;                        \
    *(bf16x8*)&Ab[((size_t)2 * 512 + tid) * 8] = t2_;                        \
    *(bf16x8*)&Ab[((size_t)3 * 512 + tid) * 8] = t3_;                        \
  }

template <int LAYER>
__device__ void rec_body(const __hip_bfloat16* __restrict__ Wcs_j,
                         const float* __restrict__ Pbase,  // L0: Psw0; L1: P1 ring
                         __hip_bfloat16* __restrict__ R,   // exchange ring area
                         float* __restrict__ out,
                         uint32_t* __restrict__ flags,
                         SharedMem& sm, int j) {
  const int tid = threadIdx.x;
  const int lane = tid & 63, w = tid >> 6;      // 8 waves
  const int lrow = lane & 15, lgrp = lane >> 4;

  uint32_t* F = flags + LAYER * 1024;           // agent stage flags f[s][t]
  uint32_t* cnt1 = flags + 2048;
  uint32_t* l1prog = flags + 2304;
  uint32_t* xccb = flags + 2560;                // [16] rendezvous xcc ids
  uint32_t* xcnt = flags + 2592;                // [2]
  uint32_t* Fl = flags + 4096 + LAYER * 1024;   // L2-local stage flags (fast)

  __hip_bfloat16* const Wl = sm.rec.Wl;
  __hip_bfloat16* const Ab = sm.rec.Ab;
  __hip_bfloat16* const st = sm.rec.st;
  float* const zl  = sm.rec.zl;
  float* const h1s = sm.rec.h1s;
  float* const h2s = sm.rec.h2s;

  const int HM = LAYER ? 1 : 7;                 // coh h ring mask (depth 2 / 8)
  __hip_bfloat16* const h1r = R + (size_t)(LAYER ? 20 : 0)  * XBUF;
  __hip_bfloat16* const h2r = R + (size_t)(LAYER ? 22 : 8)  * XBUF;
  __hip_bfloat16* const ag1 = R + (size_t)(LAYER ? 24 : 16) * XBUF;
  __hip_bfloat16* const ag2 = R + (size_t)(LAYER ? 26 : 18) * XBUF;
  // fast-mode XCD-local buffers (only touched by this layer's 8 WGs)
  __hip_bfloat16* const Lb  = R + (size_t)(32 + LAYER * 8) * XBUF;
  __hip_bfloat16* const lag1 = Lb + 0 * XBUF;   // [2] slots (t&1)
  __hip_bfloat16* const lag2 = Lb + 2 * XBUF;
  __hip_bfloat16* const lh1  = Lb + 4 * XBUF;
  __hip_bfloat16* const lh2  = Lb + 6 * XBUF;

  // rendezvous publish (before init so the L3 RTTs overlap the weight load)
  if (tid == 0) {
    uint32_t xcc;
    asm volatile("s_getreg_b32 %0, hwreg(20, 0, 32)" : "=s"(xcc));
    __hip_atomic_store(&xccb[LAYER * 8 + j], (xcc & 15u) | 256u,
                       __ATOMIC_RELAXED, __HIP_MEMORY_SCOPE_AGENT);
    asm volatile("s_waitcnt vmcnt(0)" ::: "memory");   // id visible before count
    __hip_atomic_fetch_add(&xcnt[LAYER], 1u, __ATOMIC_RELAXED, __HIP_MEMORY_SCOPE_AGENT);
  }

  // one-time init: weights -> LDS, h slices -> 0, saved page 0 -> 0
  for (int i = tid; i < WG_FRAGS; i += 512)
    *(bf16x8*)&Wl[(size_t)i * 8] = *(const bf16x8*)&Wcs_j[(size_t)i * 8];
  for (int i = tid; i < 2048; i += 512) { h1s[i] = 0.f; h2s[i] = 0.f; }
  if (LAYER == 1)
    for (int i = tid; i < 64 * 32; i += 512) {
      int row = i >> 5, c = 32 * j + (i & 31);
      if (c < SLICE_N) out[SAVED_OFF + (size_t)row * SLICE_N + c] = 0.f;
    }
  __syncthreads();
  if (tid == 0) {
    POLLGE(&xcnt[LAYER], 8);
    uint32_t v0 = __hip_atomic_load(&xccb[LAYER * 8], __ATOMIC_RELAXED, __HIP_MEMORY_SCOPE_AGENT);
    uint32_t same = 1;
    for (int q = 1; q < 8; ++q)
      same &= (__hip_atomic_load(&xccb[LAYER * 8 + q], __ATOMIC_RELAXED,
                                 __HIP_MEMORY_SCOPE_AGENT) == v0) ? 1u : 0u;
    sm.rec.fastf = same;
  }
  __syncthreads();
  const bool FM = (sm.rec.fastf != 0);

  // stage-1/3 wave constants: ct13 0,1 = z-tiles, 2,3 = r-tiles; 2 row-tiles
  const int ct13 = w >> 1, a0 = (w & 1) * 2, a1 = a0 + 1;
  const int cl13 = 16 * (ct13 & 1) + lrow;
  const int lt13 = (lgrp * 4) | ((cl13 >> 3) << 4);
  const int el13 = cl13 & 7;
  // stage-2/4 wave constants: ct24 0,1 g-tiles; a24 row-tile
  const int ct24 = w >> 2, a24 = w & 3;
  const int cl24 = 16 * ct24 + lrow;
  const int lt24 = (lgrp * 4) | ((cl24 >> 3) << 4);
  const int el24 = cl24 & 7;
  const int col24 = 32 * j + cl24;
  const int row24 = a24 * 16 + lgrp * 4;
  // publish word constants: lane -> (word row, el-half)
  const int pu = lane >> 1, phf = (lane & 1) * 4;
  const int plt13 = (ct13 & 1) * 32 + pu;   // stage-1/3 word row
  const int plt24 = ct24 * 32 + pu;         // stage-2/4 word row
  // loop-invariant publish offsets
  const size_t go13a = ((size_t)(a0 * 8 + j) * 64 + plt13) * 8 + phf;
  const size_t go13b = ((size_t)(a1 * 8 + j) * 64 + plt13) * 8 + phf;
  const size_t go24  = ((size_t)(a24 * 8 + j) * 64 + plt24) * 8 + phf;
  const size_t so13a = (size_t)(a0 * 64 + plt13) * 8 + phf;
  const size_t so13b = (size_t)(a1 * 64 + plt13) * 8 + phf;
  const size_t so24  = (size_t)(a24 * 64 + plt24) * 8 + phf;

  const float Q23 = 8388608.f, IQ23 = 1.f / 8388608.f;
  const float Q10 = 1024.f,    IQ10 = 1.f / 1024.f;

  float hr1[4] = {0.f, 0.f, 0.f, 0.f};
  float hr2[4] = {0.f, 0.f, 0.f, 0.f};

  for (int t = 0; t < T_STEPS; ++t) {
    auto LDP = [&](int g, int slot) -> float4 {
      const float* a = paddr<LAYER>(Pbase, g, t, slot, j, lane);
      if (LAYER == 1) return coh_f4(a);       // ring reuse -> must bypass caches
      return *(const float4*)a;
    };
    float4 P_s1_0, P_s1_1, P_s2, P_s3_0, P_s3_1, P_s4;
    if (LAYER == 0) {                          // independent of flags: overlap poll
      P_s1_0 = LDP(a0, ct13);      P_s1_1 = LDP(a1, ct13);
      P_s2   = LDP(a24, 4 + ct24);
      P_s3_0 = LDP(a0, 6 + ct13);  P_s3_1 = LDP(a1, 6 + ct13);
      P_s4   = LDP(a24, 10 + ct24);
    }

    // ================== stage 1: zr1 = sigma(P + h2 @ Uzr1)
    if (tid == 0) {
      if (LAYER == 1) { POLLGE(&cnt1[t], NHELP); }
      if (LAYER == 0 && t >= 8) { POLLGE(&cnt1[t - 8], NHELP); } // coh h-ring WAR
      if (t > 0) {
        if (FM) { L2POLLGE(&Fl[3 * 256 + t - 1], 8); }
        else    { POLLGE(&F[3 * 256 + t - 1], 8); }
      }
    }
    __syncthreads();
    if (FM) l1_inv();
    if (LAYER == 1) {
      P_s1_0 = LDP(a0, ct13);      P_s1_1 = LDP(a1, ct13);
      P_s2   = LDP(a24, 4 + ct24);
      P_s3_0 = LDP(a0, 6 + ct13);  P_s3_1 = LDP(a1, 6 + ct13);
      P_s4   = LDP(a24, 10 + ct24);
    }
    if (t == 0) {
      bf16x8 zz = {0, 0, 0, 0, 0, 0, 0, 0};
#pragma unroll
      for (int q = 0; q < 4; ++q) *(bf16x8*)&Ab[((size_t)q * 512 + tid) * 8] = zz;
    } else {
      const __hip_bfloat16* src = FM ? (lh2 + (size_t)((t - 1) & 1) * XBUF)
                                     : (h2r + (size_t)((t - 1) & HM) * XBUF);
      AB_FILL_ANY(src, FM);
    }
    __syncthreads();
    {
      f32x4 c0 = (f32x4){0.f, 0.f, 0.f, 0.f}, c1 = c0;
#pragma unroll
      for (int kt = 0; kt < 8; ++kt) {
        bf16x8 A0 = *(const bf16x8*)&Ab[((a0 * 8 + kt) * 64 + lane) * 8];
        bf16x8 A1 = *(const bf16x8*)&Ab[((a1 * 8 + kt) * 64 + lane) * 8];
        bf16x8 B  = *(const bf16x8*)&Wl[((ct13 * 8 + kt) * 64 + lane) * 8];
        c0 = mfma16(A0, B, c0);
        c1 = mfma16(A1, B, c1);
      }
      if (ct13 < 2) {
#pragma unroll
        for (int rr = 0; rr < 4; ++rr) {
          zl[(a0 * 16 + lgrp * 4 + rr) * 32 + cl13] = 0.875f * sigm_f(c0[rr] + P_s1_0[rr]) + 0.125f;
          zl[(a1 * 16 + lgrp * 4 + rr) * 32 + cl13] = 0.875f * sigm_f(c1[rr] + P_s1_1[rr]) + 0.125f;
        }
      } else {
#pragma unroll
        for (int rr = 0; rr < 4; ++rr) {
          float r0 = sigm_f(c0[rr] + P_s1_0[rr]);
          float r1 = sigm_f(c1[rr] + P_s1_1[rr]);
          st[(a0 * 64 + lt13 + rr) * 8 + el13] =
              __float2bfloat16(r0 * h2s[(a0 * 16 + lgrp * 4 + rr) * 32 + cl13]);
          st[(a1 * 64 + lt13 + rr) * 8 + el13] =
              __float2bfloat16(r1 * h2s[(a1 * 16 + lgrp * 4 + rr) * 32 + cl13]);
        }
        CFENCE();   // DS in-order per wave: readback below sees writes above
        unsigned long long v0 = *(const unsigned long long*)&st[so13a];
        unsigned long long v1 = *(const unsigned long long*)&st[so13b];
        __hip_bfloat16* dst = (FM ? lag1 : ag1) + (size_t)(t & 1) * XBUF;
        if (FM) {
          *(unsigned long long*)&dst[go13a] = v0;
          *(unsigned long long*)&dst[go13b] = v1;
        } else {
          coh_store_u64(&dst[go13a], v0);
          coh_store_u64(&dst[go13b], v1);
        }
      }
    }
    __syncthreads();   // drains DS + all waves' stores -> data at L2/L3
    if (tid == 0) {
      if (FM) l2_flag_add(&Fl[0 * 256 + t]);
      else __hip_atomic_fetch_add(&F[0 * 256 + t], 1u, __ATOMIC_RELAXED, __HIP_MEMORY_SCOPE_AGENT);
    }

    // ================== stage 2: g1 = tanh(P + ag1 @ Ug1); h1 update
    if (tid == 0) {
      if (FM) { L2POLLGE(&Fl[0 * 256 + t], 8); }
      else    { POLLGE(&F[0 * 256 + t], 8); }
    }
    __syncthreads();
    if (FM) l1_inv();
    {
      const __hip_bfloat16* src = (FM ? lag1 : ag1) + (size_t)(t & 1) * XBUF;
      AB_FILL_ANY(src, FM);
    }
    __syncthreads();
    {
      f32x4 c = (f32x4){0.f, 0.f, 0.f, 0.f};
#pragma unroll
      for (int kt = 0; kt < 8; ++kt) {
        bf16x8 A = *(const bf16x8*)&Ab[((a24 * 8 + kt) * 64 + lane) * 8];
        bf16x8 B = *(const bf16x8*)&Wl[((32 + ct24 * 8 + kt) * 64 + lane) * 8];
        c = mfma16(A, B, c);
      }
#pragma unroll
      for (int rr = 0; rr < 4; ++rr) {
        float gv = tanh_f(c[rr] + P_s2[rr]);
        float z  = zl[(row24 + rr) * 32 + cl24];
        float zq = floorf(z * Q10) * IQ10;
        float h = hr1[rr];
        h = floorf(h * zq * Q23) * IQ23;
        h = h + rintf((1.f - z) * gv * Q23) * IQ23;
        hr1[rr] = h;
        h1s[(row24 + rr) * 32 + cl24] = h;
        st[(a24 * 64 + lt24 + rr) * 8 + el24] = __float2bfloat16(h);
        int row = row24 + rr;
        if (LAYER == 1 && col24 < SLICE_N)
          out[SAVED_OFF + (size_t)(t + 1) * (BATCH * SLICE_N) + (size_t)row * SLICE_N + col24] = h;
        if (t == T_STEPS - 1)
          out[(size_t)LAYER * (BATCH * HID) + (size_t)row * HID + col24] = h;
      }
      CFENCE();
      unsigned long long v = *(const unsigned long long*)&st[so24];
      if (FM) {
        *(unsigned long long*)&(lh1 + (size_t)(t & 1) * XBUF)[go24] = v;
        if (LAYER == 0)   // helper-facing coh ring (depth 8)
          coh_store_u64(&(h1r + (size_t)(t & 7) * XBUF)[go24], v);
      } else {
        coh_store_u64(&(h1r + (size_t)(t & HM) * XBUF)[go24], v);
      }
    }
    __syncthreads();
    if (tid == 0) {
      if (FM) l2_flag_add(&Fl[1 * 256 + t]);
      else __hip_atomic_fetch_add(&F[1 * 256 + t], 1u, __ATOMIC_RELAXED, __HIP_MEMORY_SCOPE_AGENT);
    }

    // ================== stage 3: zr2 = sigma(P + h1 @ Uzr2)
    if (tid == 0) {
      if (FM) { L2POLLGE(&Fl[1 * 256 + t], 8); }
      else    { POLLGE(&F[1 * 256 + t], 8); }
    }
    __syncthreads();
    if (FM) l1_inv();
    {
      const __hip_bfloat16* src = FM ? (lh1 + (size_t)(t & 1) * XBUF)
                                     : (h1r + (size_t)(t & HM) * XBUF);
      AB_FILL_ANY(src, FM);
    }
    __syncthreads();
    {
      f32x4 c0 = (f32x4){0.f, 0.f, 0.f, 0.f}, c1 = c0;
#pragma unroll
      for (int kt = 0; kt < 8; ++kt) {
        bf16x8 A0 = *(const bf16x8*)&Ab[((a0 * 8 + kt) * 64 + lane) * 8];
        bf16x8 A1 = *(const bf16x8*)&Ab[((a1 * 8 + kt) * 64 + lane) * 8];
        bf16x8 B  = *(const bf16x8*)&Wl[((48 + ct13 * 8 + kt) * 64 + lane) * 8];
        c0 = mfma16(A0, B, c0);
        c1 = mfma16(A1, B, c1);
      }
      if (ct13 < 2) {
#pragma unroll
        for (int rr = 0; rr < 4; ++rr) {
          zl[(a0 * 16 + lgrp * 4 + rr) * 32 + cl13] = 0.875f * sigm_f(c0[rr] + P_s3_0[rr]) + 0.125f;
          zl[(a1 * 16 + lgrp * 4 + rr) * 32 + cl13] = 0.875f * sigm_f(c1[rr] + P_s3_1[rr]) + 0.125f;
        }
      } else {
#pragma unroll
        for (int rr = 0; rr < 4; ++rr) {
          float r0 = sigm_f(c0[rr] + P_s3_0[rr]);
          float r1 = sigm_f(c1[rr] + P_s3_1[rr]);
          st[(a0 * 64 + lt13 + rr) * 8 + el13] =
              __float2bfloat16(r0 * h1s[(a0 * 16 + lgrp * 4 + rr) * 32 + cl13]);
          st[(a1 * 64 + lt13 + rr) * 8 + el13] =
              __float2bfloat16(r1 * h1s[(a1 * 16 + lgrp * 4 + rr) * 32 + cl13]);
        }
        CFENCE();
        unsigned long long v0 = *(const unsigned long long*)&st[so13a];
        unsigned long long v1 = *(const unsigned long long*)&st[so13b];
        __hip_bfloat16* dst = (FM ? lag2 : ag2) + (size_t)(t & 1) * XBUF;
        if (FM) {
          *(unsigned long long*)&dst[go13a] = v0;
          *(unsigned long long*)&dst[go13b] = v1;
        } else {
          coh_store_u64(&dst[go13a], v0);
          coh_store_u64(&dst[go13b], v1);
        }
      }
    }
    __syncthreads();
    if (tid == 0) {
      if (FM) l2_flag_add(&Fl[2 * 256 + t]);
      else __hip_atomic_fetch_add(&F[2 * 256 + t], 1u, __ATOMIC_RELAXED, __HIP_MEMORY_SCOPE_AGENT);
    }

    // ================== stage 4: g2 = tanh(P + ag2 @ Ug2); h2 update
    if (tid == 0) {
      if (FM) { L2POLLGE(&Fl[2 * 256 + t], 8); }
      else    { POLLGE(&F[2 * 256 + t], 8); }
    }
    __syncthreads();
    if (FM) l1_inv();
    {
      const __hip_bfloat16* src = (FM ? lag2 : ag2) + (size_t)(t & 1) * XBUF;
      AB_FILL_ANY(src, FM);
    }
    __syncthreads();
    {
      f32x4 c = (f32x4){0.f, 0.f, 0.f, 0.f};
#pragma unroll
      for (int kt = 0; kt < 8; ++kt) {
        bf16x8 A = *(const bf16x8*)&Ab[((a24 * 8 + kt) * 64 + lane) * 8];
        bf16x8 B = *(const bf16x8*)&Wl[((80 + ct24 * 8 + kt) * 64 + lane) * 8];
        c = mfma16(A, B, c);
      }
#pragma unroll
      for (int rr = 0; rr < 4; ++rr) {
        float gv = tanh_f(c[rr] + P_s4[rr]);
        float z  = zl[(row24 + rr) * 32 + cl24];
        float zq = floorf(z * Q10) * IQ10;
        float h = hr2[rr];
        h = floorf(h * zq * Q23) * IQ23;
        h = h + rintf((1.f - z) * gv * Q23) * IQ23;
        hr2[rr] = h;
        h2s[(row24 + rr) * 32 + cl24] = h;
        st[(a24 * 64 + lt24 + rr) * 8 + el24] = __float2bfloat16(h);
        int row = row24 + rr;
        if (t == T_STEPS - 1)
          out[(size_t)LAYER * (BATCH * HID) + (size_t)row * HID + HALF + col24] = h;
      }
      CFENCE();
      unsigned long long v = *(const unsigned long long*)&st[so24];
      if (FM) {
        *(unsigned long long*)&(lh2 + (size_t)(t & 1) * XBUF)[go24] = v;
        if (LAYER == 0)
          coh_store_u64(&(h2r + (size_t)(t & 7) * XBUF)[go24], v);
      } else {
        coh_store_u64(&(h2r + (size_t)(t & HM) * XBUF)[go24], v);
      }
    }
    __syncthreads();
    if (tid == 0) {
      if (FM) {
        l2_flag_add(&Fl[3 * 256 + t]);
        if (LAYER == 0)   // helper-facing: coh h stores drained by the barrier
          __hip_atomic_fetch_add(&F[3 * 256 + t], 1u, __ATOMIC_RELAXED, __HIP_MEMORY_SCOPE_AGENT);
        if (LAYER == 1)
          __hip_atomic_store(&l1prog[j], (uint32_t)(t + 1), __ATOMIC_RELAXED, __HIP_MEMORY_SCOPE_AGENT);
      } else {
        __hip_atomic_fetch_add(&F[3 * 256 + t], 1u, __ATOMIC_RELAXED, __HIP_MEMORY_SCOPE_AGENT);
        if (LAYER == 1)
          __hip_atomic_store(&l1prog[j], (uint32_t)(t + 1), __ATOMIC_RELAXED, __HIP_MEMORY_SCOPE_AGENT);
      }
    }
  }
}

// helper: P1(t)[:, n0:n0+64] = h0(t) @ Wx1-slice + bias. A-frags come from the
// layer-0 coh h exchange ring (identical bf16 values / K-order as before).
__device__ void helper_body(const __hip_bfloat16* __restrict__ WxT1,
                            const float* __restrict__ bias1,
                            const __hip_bfloat16* __restrict__ R,
                            float* __restrict__ P1ring,
                            uint32_t* __restrict__ flags,
                            SharedMem& sm, int n) {
  const int tid = threadIdx.x;
  const int lane = tid & 63, w = tid >> 6;
  const int lrow = lane & 15, lgrp = lane >> 4;
  const int n0 = n * 64;

  uint32_t* F0 = flags;                  // layer-0 agent stage flags
  uint32_t* cnt1 = flags + 2048;
  uint32_t* l1prog = flags + 2304;
  const __hip_bfloat16* h1r = R;         // L0 coh h rings (depth 8)
  const __hip_bfloat16* h2r = R + (size_t)8 * XBUF;

  for (int i = tid; i < 64 * 64; i += 512) {
    int c = i >> 6, k8 = (i & 63) * 8;
    *(bf16x8*)&sm.hlp.Bs[c][k8] = *(const bf16x8*)&WxT1[(size_t)(n0 + c) * 512 + k8];
  }
  if (tid < 64) sm.hlp.bias[tid] = bias1[n0 + tid];
  __syncthreads();

  const int mt = w & 3, chb = (w >> 2) * 2;   // row-tile, col-subtile pair

  for (int t = 0; t < T_STEPS; ++t) {
    if (tid == 0) {
      POLLGE(&F0[3 * 256 + t], 8);            // h1,h2 of step t published
      if (t >= RING_D) {                      // P1-ring WAR vs layer-1
        for (;;) {
          uint32_t mm = 0xffffffffu;
#pragma unroll
          for (int q = 0; q < 8; ++q) {
            uint32_t v = __hip_atomic_load(&l1prog[q], __ATOMIC_RELAXED, __HIP_MEMORY_SCOPE_AGENT);
            mm = v < mm ? v : mm;
          }
          if (mm + (uint32_t)(RING_D - 1) >= (uint32_t)t) break;
          __builtin_amdgcn_s_sleep(1);
        }
      }
    }
    __syncthreads();
    {
      const char* s1 = (const char*)&h1r[(size_t)(t & 7) * XBUF] + (size_t)tid * 16;
      const char* s2 = (const char*)&h2r[(size_t)(t & 7) * XBUF] + (size_t)tid * 16;
      bf16x8 tA[8];
#pragma unroll
      for (int k = 0; k < 4; ++k) tA[k] = coh_frag(s1 + (size_t)k * 8192);
#pragma unroll
      for (int k = 4; k < 8; ++k) tA[k] = coh_frag(s2 + (size_t)(k - 4) * 8192);
#pragma unroll
      for (int k = 0; k < 8; ++k) *(bf16x8*)&sm.hlp.As[(size_t)(k * 512 + tid) * 8] = tA[k];
    }
    __syncthreads();
#pragma unroll
    for (int q = 0; q < 2; ++q) {
      int ch = chb + q;
      f32x4 c = (f32x4){0.f, 0.f, 0.f, 0.f};
#pragma unroll
      for (int kt = 0; kt < 16; ++kt) {
        const bf16x8 A = *(const bf16x8*)&sm.hlp.As[
            kt < 8 ? (size_t)((mt * 8 + kt) * 64 + lane) * 8
                   : (size_t)XBUF + (size_t)((mt * 8 + (kt - 8)) * 64 + lane) * 8];
        const bf16x8 B = *(const bf16x8*)&sm.hlp.Bs[ch * 16 + lrow][kt * 32 + lgrp * 8];
        c = mfma16(A, B, c);
      }
      int colb = n0 + ch * 16;               // wave-uniform
      int slot, wt;
      if (colb < 512)       { int cc = colb;        wt = (cc & 255) >> 5; slot = (cc >> 8) * 2 + ((cc >> 4) & 1); }
      else if (colb < 768)  { int cc = colb - 512;  wt = cc >> 5;         slot = 4 + ((cc >> 4) & 1); }
      else if (colb < 1280) { int cc = colb - 768;  wt = (cc & 255) >> 5; slot = 6 + (cc >> 8) * 2 + ((cc >> 4) & 1); }
      else                  { int cc = colb - 1280; wt = cc >> 5;         slot = 10 + ((cc >> 4) & 1); }
      float bv = sm.hlp.bias[ch * 16 + lrow];
      union { float4 f; unsigned long long u[2]; } uv;
      uv.f.x = c[0] + bv; uv.f.y = c[1] + bv; uv.f.z = c[2] + bv; uv.f.w = c[3] + bv;
      size_t off = (((size_t)mt * RING_D + (t & (RING_D - 1))) * 12 + slot) * PSLOT +
                   (size_t)wt * 256 + (size_t)lane * 4;
      unsigned long long* d = (unsigned long long*)&P1ring[off];
      coh_store_u64(d, uv.u[0]);
      coh_store_u64(d + 1, uv.u[1]);
    }
    __syncthreads();   // drains vmcnt: all coherent stores visible at L3
    if (tid == 0)
      __hip_atomic_fetch_add(&cnt1[t], 1u, __ATOMIC_RELAXED, __HIP_MEMORY_SCOPE_AGENT);
  }
}

__global__ __attribute__((amdgpu_waves_per_eu(2))) __launch_bounds__(512)
void fused_kernel(const __hip_bfloat16* __restrict__ Wcs,
                  const float* __restrict__ Psw0,
                  float* __restrict__ P1ring,
                  const __hip_bfloat16* __restrict__ WxT1,
                  const float* __restrict__ bias1,
                  float* __restrict__ out,
                  __hip_bfloat16* __restrict__ R,
                  uint32_t* __restrict__ flags) {
  __shared__ SharedMem sm;
  const int bid = blockIdx.x;
  const int xslot = bid & 7, idx = bid >> 3;   // presumed XCD, slot-on-XCD
  if (xslot == 0)
    rec_body<0>(Wcs + (size_t)idx * WG_FRAGS * 8, Psw0, R, out, flags, sm, idx);
  else if (xslot == 1)
    rec_body<1>(Wcs + (size_t)(8 + idx) * WG_FRAGS * 8, P1ring, R, out, flags, sm, idx);
  else if (idx < 4)
    helper_body(WxT1, bias1, R, P1ring, flags, sm, (xslot - 2) * 4 + idx);
}

// ---------------------------------------------------------------- launch
extern "C" void kernel_launch(void* const* d_in, const int* in_sizes, int n_in,
                              void* d_out, int out_size, void* d_ws, size_t ws_size,
                              hipStream_t stream) {
  const int*   seq = (const int*)d_in[0];
  const float* emb = (const float*)d_in[1];
  AllW aw;
  for (int l = 0; l < 2; ++l)
    for (int s = 0; s < 4; ++s) {
      aw.W[l * 4 + s] = (const float*)d_in[2 + l * 8 + s * 2];
      aw.b[l * 4 + s] = (const float*)d_in[2 + l * 8 + s * 2 + 1];
    }

  uint8_t* wp = (uint8_t*)d_ws;
  float* Psw = (float*)wp;                   wp += (size_t)4 * 256 * PSTEP * 4;        // 100.7 MB (P0)
  __hip_bfloat16* X0 = (__hip_bfloat16*)wp;  wp += (size_t)MROWS * HID * 2;            // 16.8 MB (X0 -> P1 ring)
  __hip_bfloat16* R  = (__hip_bfloat16*)wp;  wp += (size_t)MROWS * HID * 2;            // 16.8 MB (exchange rings + L2-local bufs)
  __hip_bfloat16* Wcs = (__hip_bfloat16*)wp; wp += (size_t)2 * 8 * WG_FRAGS * 8 * 2;   // 1.6 MB
  __hip_bfloat16* WxT = (__hip_bfloat16*)wp; wp += (size_t)2 * NCOLS * 512 * 2;        // 3.1 MB
  float* biasAll = (float*)wp;               wp += (size_t)2 * NCOLS * 4;
  uint32_t* flags = (uint32_t*)wp;           wp += 32768;  // F|cnt1|l1prog|xcc | Fl

  float* out = (float*)d_out;

  const int prepTot = 2 * 8 * WG_FRAGS + 2 * NCOLS * 64 + 2 * NCOLS;
  const int prepN = (prepTot + 255) / 256;
  prep_weights<<<prepN, 256, 0, stream>>>(aw, Wcs, WxT, biasAll, flags);
  embed_gather<<<(MROWS * 128) / 256, 256, 0, stream>>>(seq, emb, X0);

  gemm_p<<<dim3(24, 256), 256, 0, stream>>>(X0, WxT, biasAll, Psw);
  // X0 dead after gemm_p -> reuse as P1 ring (32 steps deep)
  fused_kernel<<<64, 512, 0, stream>>>(
      Wcs, Psw, (float*)X0, WxT + (size_t)NCOLS * 512, biasAll + NCOLS,
      out, R, flags);
}